// Round 5
// baseline (336.524 us; speedup 1.0000x reference)
//
#include <hip/hip_runtime.h>
#include <hip/hip_bf16.h>
#include <math.h>

#define BB   2
#define SS   2048
#define DIM  1024
#define NH   16
#define HD   64
#define MTOT (BB * SS)   // 4096

typedef unsigned short ushortT;
typedef __attribute__((ext_vector_type(8))) short short8v;   // 8 bf16 (4 VGPRs)
typedef __attribute__((ext_vector_type(4))) float float4v;   // 4 fp32 acc
typedef __attribute__((ext_vector_type(16))) float float16v; // 16 fp32 acc (32x32 MFMA)

union FragU { short8v v; unsigned short us[8]; unsigned int u[4]; };

__device__ inline unsigned short f2bf(float x) {             // fp32 -> bf16 RNE
    unsigned u = __builtin_bit_cast(unsigned, x);
    u += 0x7fffu + ((u >> 16) & 1u);
    return (unsigned short)(u >> 16);
}
__device__ inline float bf2f(unsigned short h) {
    unsigned u = ((unsigned)h) << 16;
    return __builtin_bit_cast(float, u);
}
// truncation split: hi = trunc-to-bf16(x), lo = trunc-to-bf16(x - hi)
__device__ inline void split_tr(float x, unsigned short& hi, unsigned short& lo) {
    unsigned u = __builtin_bit_cast(unsigned, x);
    hi = (unsigned short)(u >> 16);
    float hf = __builtin_bit_cast(float, u & 0xffff0000u);
    lo = (unsigned short)(__builtin_bit_cast(unsigned, x - hf) >> 16);
}
__device__ inline void split4(const float4& x, short4& hi, short4& lo) {
    unsigned short h0 = f2bf(x.x), h1 = f2bf(x.y), h2 = f2bf(x.z), h3 = f2bf(x.w);
    hi = make_short4((short)h0, (short)h1, (short)h2, (short)h3);
    lo = make_short4((short)f2bf(x.x - bf2f(h0)), (short)f2bf(x.y - bf2f(h1)),
                     (short)f2bf(x.z - bf2f(h2)), (short)f2bf(x.w - bf2f(h3)));
}
// async global->LDS, 16 B per lane (dest = wave-uniform base + lane*16)
__device__ inline void gld_lds16(const void* g, void* l) {
    __builtin_amdgcn_global_load_lds(
        (const __attribute__((address_space(1))) void*)g,
        (__attribute__((address_space(3))) void*)l, 16, 0, 0);
}
// packed RNE bf16 convert: lo16 = bf16(a), hi16 = bf16(b)
__device__ inline unsigned cvt_pk_bf16(float a, float b) {
    unsigned r;
    asm("v_cvt_pk_bf16_f32 %0, %1, %2" : "=v"(r) : "v"(a), "v"(b));
    return r;
}
// v_permlane32_swap_b32: a' = [a(0:31), b(0:31)], b' = [a(32:63), b(32:63)]
__device__ inline void permlane32_swap(unsigned &a, unsigned &b) {
    asm("v_permlane32_swap_b32 %0, %1" : "+v"(a), "+v"(b));
}

// ---------------------------------------------------------------------------
// fp32 -> bf16 hi/lo elementwise split (X)
// ---------------------------------------------------------------------------
__global__ __launch_bounds__(256) void convert_split_kernel(
    const float* __restrict__ in, ushortT* __restrict__ hi, ushortT* __restrict__ lo, int n4)
{
    int t = blockIdx.x * 256 + threadIdx.x;
    if (t < n4) {
        float4 x = ((const float4*)in)[t];
        short4 h, l; split4(x, h, l);
        ((short4*)hi)[t] = h;
        ((short4*)lo)[t] = l;
    }
}

// ---------------------------------------------------------------------------
// W (1024x1024 fp32, K-major) -> W^T (bf16 hi/lo, N-major rows of K)
// ---------------------------------------------------------------------------
__global__ __launch_bounds__(256) void transpose_split_kernel(
    const float* __restrict__ W0, const float* __restrict__ W1,
    const float* __restrict__ W2, const float* __restrict__ W3,
    ushortT* __restrict__ WtH, ushortT* __restrict__ WtL)
{
    const int z = blockIdx.z;
    const float* __restrict__ W = (z == 0) ? W0 : (z == 1) ? W1 : (z == 2) ? W2 : W3;
    ushortT* H = WtH + (size_t)z * 1024 * 1024;
    ushortT* L = WtL + (size_t)z * 1024 * 1024;

    __shared__ float T[64][65];
    const int k0 = blockIdx.y * 64, n0 = blockIdx.x * 64;
    const int tid = threadIdx.x;
    const int c4 = (tid & 15) * 4;

#pragma unroll
    for (int i = 0; i < 4; i++) {
        int r = (tid >> 4) + 16 * i;
        *(float4*)&T[r][c4] = *(const float4*)(W + (size_t)(k0 + r) * 1024 + n0 + c4);
    }
    __syncthreads();
#pragma unroll
    for (int i = 0; i < 4; i++) {
        int n = (tid >> 4) + 16 * i;
        float4 vv = make_float4(T[c4 + 0][n], T[c4 + 1][n], T[c4 + 2][n], T[c4 + 3][n]);
        short4 h, l; split4(vv, h, l);
        *(short4*)&H[(size_t)(n0 + n) * 1024 + k0 + c4] = h;
        *(short4*)&L[(size_t)(n0 + n) * 1024 + k0 + c4] = l;
    }
}

// ---------------------------------------------------------------------------
// Split-bf16 MFMA GEMM.
//  z==2 (V projection): stores output DIRECTLY as split-bf16 frag-major
//        32x32x16 V^T A-op tiles (layout verified rounds 1-4).
//  z==1 (K projection): NEW — stores output directly as split-bf16 frag-major
//        32x32x16 K A-op tiles via per-wave LDS-bounce transpose (replaces the
//        kv_convert kernel; values bit-identical: kv_convert only round-tripped
//        the same fp32 acc through global).
//  z==0: fp32 rows (Q projection / output projection).
// launch_bounds (256,2): 2 blocks/CU — (256,3) cost ~18 µs via L2 pressure
// (round 4->5 non-attn delta attribution); reverted.
// ---------------------------------------------------------------------------
__global__ __launch_bounds__(256, 2) void gemm_bt_split_kernel(
    const ushortT* __restrict__ Ah, const ushortT* __restrict__ Al,
    const ushortT* __restrict__ BtH, const ushortT* __restrict__ BtL,
    float* __restrict__ Y0, float* __restrict__ Y1,
    ushortT* __restrict__ VhG, ushortT* __restrict__ VlG,
    ushortT* __restrict__ KhGp, ushortT* __restrict__ KlGp)
{
    const int z = blockIdx.z;
    const ushortT* __restrict__ Bh = BtH + (size_t)z * 1024 * 1024;
    const ushortT* __restrict__ Bl = BtL + (size_t)z * 1024 * 1024;

    const int K = 1024, N = 1024;
    const int m0 = blockIdx.y * 128;
    const int n0 = blockIdx.x * 128;

    __shared__ __align__(16) ushortT AhS[128 * 32];
    __shared__ __align__(16) ushortT AlS[128 * 32];
    __shared__ __align__(16) ushortT BhS[128 * 32];
    __shared__ __align__(16) ushortT BlS[128 * 32];
    __shared__ __align__(16) float EPI[4][32][68];   // K-epilogue bounce (34.8 KB)

    const int tid  = threadIdx.x;
    const int wave = tid >> 6, lane = tid & 63;
    const int quad = lane >> 4, l15 = lane & 15;
    const int l31 = lane & 31, hi5g = lane >> 5;
    const int wm = wave >> 1, wn = wave & 1;

    const int s0 = tid, s1 = tid + 256;
    const int ar0 = s0 >> 2, ak0 = (s0 & 3) * 8;
    const int ar1 = s1 >> 2, ak1 = (s1 & 3) * 8;

    float4v acc[4][4];
#pragma unroll
    for (int i = 0; i < 4; i++)
#pragma unroll
        for (int j = 0; j < 4; j++) acc[i][j] = (float4v){0.f, 0.f, 0.f, 0.f};

    for (int k0 = 0; k0 < K; k0 += 32) {
        __syncthreads();
        gld_lds16(Ah + (size_t)(m0 + ar0) * K + k0 + ak0, &AhS[s0 * 8]);
        gld_lds16(Ah + (size_t)(m0 + ar1) * K + k0 + ak1, &AhS[s1 * 8]);
        gld_lds16(Al + (size_t)(m0 + ar0) * K + k0 + ak0, &AlS[s0 * 8]);
        gld_lds16(Al + (size_t)(m0 + ar1) * K + k0 + ak1, &AlS[s1 * 8]);
        gld_lds16(Bh + (size_t)(n0 + ar0) * K + k0 + ak0, &BhS[s0 * 8]);
        gld_lds16(Bh + (size_t)(n0 + ar1) * K + k0 + ak1, &BhS[s1 * 8]);
        gld_lds16(Bl + (size_t)(n0 + ar0) * K + k0 + ak0, &BlS[s0 * 8]);
        gld_lds16(Bl + (size_t)(n0 + ar1) * K + k0 + ak1, &BlS[s1 * 8]);
        __syncthreads();

        FragU ah[4], al[4], bh[4], bl[4];
#pragma unroll
        for (int t = 0; t < 4; t++) {
            ah[t].v = *(const short8v*)&AhS[(wm * 64 + t * 16 + l15) * 32 + quad * 8];
            al[t].v = *(const short8v*)&AlS[(wm * 64 + t * 16 + l15) * 32 + quad * 8];
            bh[t].v = *(const short8v*)&BhS[(wn * 64 + t * 16 + l15) * 32 + quad * 8];
            bl[t].v = *(const short8v*)&BlS[(wn * 64 + t * 16 + l15) * 32 + quad * 8];
        }
#pragma unroll
        for (int mt = 0; mt < 4; mt++)
#pragma unroll
            for (int nt = 0; nt < 4; nt++) {
                acc[mt][nt] = __builtin_amdgcn_mfma_f32_16x16x32_bf16(ah[mt].v, bh[nt].v, acc[mt][nt], 0, 0, 0);
                acc[mt][nt] = __builtin_amdgcn_mfma_f32_16x16x32_bf16(ah[mt].v, bl[nt].v, acc[mt][nt], 0, 0, 0);
                acc[mt][nt] = __builtin_amdgcn_mfma_f32_16x16x32_bf16(al[mt].v, bh[nt].v, acc[mt][nt], 0, 0, 0);
            }
    }

    if (z == 2) {
        // ---- V epilogue: direct frag-major split-bf16 V^T A-op tile store ----
        // acc element: (kv_local = mt*16 + quad*4 + r, d_local = nt*16 + l15)
        // target frag f = (nt>>1)*4 + mt, lane_t = (quad>>1)*32 + (nt&1)*16 + l15,
        // j = (quad&1)*4 + r  -> r-consecutive
        const int b  = m0 >> 11;
        const int jb = ((m0 & 2047) >> 6) + wm;
        const int h  = (n0 >> 6) + wn;
        const size_t tb = (size_t)((b * 16 + h) * 32 + jb) * 4096;
        ushortT* vh = VhG + tb;
        ushortT* vl = VlG + tb;
#pragma unroll
        for (int mt = 0; mt < 4; mt++)
#pragma unroll
            for (int nt = 0; nt < 4; nt++) {
                const int off = ((((nt >> 1) * 4 + mt) * 64 +
                                  (quad >> 1) * 32 + (nt & 1) * 16 + l15) * 8) +
                                (quad & 1) * 4;
                float4 vv = make_float4(acc[mt][nt][0], acc[mt][nt][1],
                                        acc[mt][nt][2], acc[mt][nt][3]);
                unsigned short h0, l0, h1, l1, h2, l2, h3, l3;
                split_tr(vv.x, h0, l0); split_tr(vv.y, h1, l1);
                split_tr(vv.z, h2, l2); split_tr(vv.w, h3, l3);
                *(short4*)&vh[off] = make_short4((short)h0, (short)h1, (short)h2, (short)h3);
                *(short4*)&vl[off] = make_short4((short)l0, (short)l1, (short)l2, (short)l3);
            }
    } else if (z == 1 && KhGp != nullptr) {
        // ---- K epilogue: LDS-bounce transpose to K A-op frag tiles ----
        // K A-op frag layout (= kv_convert's): frag f = ds*2 + kvt,
        //   element (kv = kvt*32 + (lane&31), d = ds*16 + (lane>>5)*8 + j).
        // acc holds (kv_l = mt*16+quad*4+r, d_l = nt*16+l15): 4 consecutive kv
        // per thread for one d -> transpose via wave-local LDS [32][68] halves.
        const int b  = m0 >> 11;
        const int jb = ((m0 & 2047) >> 6) + wm;
        const int h  = (n0 >> 6) + wn;
        const size_t tb = (size_t)((b * 16 + h) * 32 + jb) * 4096;
        float (*EP)[68] = EPI[wave];
#pragma unroll
        for (int kvt = 0; kvt < 2; kvt++) {
            // write this wave's half-tile (32 kv x 64 d) to wave-local LDS
#pragma unroll
            for (int mh = 0; mh < 2; mh++) {
                const int mt = kvt * 2 + mh;
#pragma unroll
                for (int nt = 0; nt < 4; nt++)
#pragma unroll
                    for (int r = 0; r < 4; r++)
                        EP[mh * 16 + quad * 4 + r][nt * 16 + l15] = acc[mt][nt][r];
            }
            // wave-local region: lgkmcnt orders write->read, no barrier
#pragma unroll
            for (int ds = 0; ds < 4; ds++) {
                const int d0 = ds * 16 + hi5g * 8;
                float4 va = *(const float4*)&EP[l31][d0];
                float4 vb = *(const float4*)&EP[l31][d0 + 4];
                float ev[8] = {va.x, va.y, va.z, va.w, vb.x, vb.y, vb.z, vb.w};
                ushortT hv[8], lv[8];
#pragma unroll
                for (int j = 0; j < 8; j++) split_tr(ev[j], hv[j], lv[j]);
                const size_t o8 = tb + (size_t)(ds * 2 + kvt) * 512 + lane * 8;
                *(short4*)&KhGp[o8]     = *(short4*)&hv[0];
                *(short4*)&KhGp[o8 + 4] = *(short4*)&hv[4];
                *(short4*)&KlGp[o8]     = *(short4*)&lv[0];
                *(short4*)&KlGp[o8 + 4] = *(short4*)&lv[4];
            }
        }
    } else {
        float* __restrict__ Y = (z == 0) ? Y0 : Y1;
#pragma unroll
        for (int mt = 0; mt < 4; mt++)
#pragma unroll
            for (int r = 0; r < 4; r++) {
                const int row = m0 + wm * 64 + mt * 16 + quad * 4 + r;
                float* yp = Y + (size_t)row * N + n0 + wn * 64 + l15;
#pragma unroll
                for (int nt = 0; nt < 4; nt++)
                    yp[nt * 16] = acc[mt][nt][r];
            }
    }
}

// ---------------------------------------------------------------------------
// MFMA attention, 32x32x16. Round-5: round-4 software pipeline (QK(jb+1)
// issued before finish(jb); K 2-ahead, V 1-ahead; one barrier/iter)
// + T5 s_setprio(1) around MFMA clusters (QK per-ds groups, PV per-kvs
// groups with V ds_reads hoisted) — scheduler prefers MFMA-issuing waves
// while sibling waves run softmax VALU / LDS staging.
// Math identical to round-3/4 passing kernels (exact reference recurrence:
// O = (alpha*O + P@V)/l_new EVERY kv step — per-step division is SEMANTIC,
// round-2 lesson: it does NOT telescope).
// ---------------------------------------------------------------------------
__global__ __launch_bounds__(256, 2) void attn_mfma_kernel(
    const float* __restrict__ q,
    const ushortT* __restrict__ KhG, const ushortT* __restrict__ KlG,
    const ushortT* __restrict__ VhG, const ushortT* __restrict__ VlG,
    ushortT* __restrict__ Oh, ushortT* __restrict__ Ol)
{
    // layout (ushort units): K0 @0, K1 @8192, V0 @16384, V1 @24576
    // each Kx/Vx = {hi 4096, lo 4096}
    __shared__ __align__(16) ushortT SMEM[32768];   // 64 KiB

    const int tid  = threadIdx.x;
    const int wave = tid >> 6, lane = tid & 63;
    const int l31 = lane & 31, hi5 = lane >> 5;
    const int bh = blockIdx.y, b = bh >> 4, h = bh & 15;
    const size_t base = (size_t)b * SS * DIM + (size_t)h * HD;
    const int qs0 = blockIdx.x * 128 + wave * 32;
    const int lane8 = lane * 8;
    const int sl0 = wave * 128 + lane, sl1 = sl0 + 64;

    ushortT* K0 = SMEM;
    ushortT* K1 = SMEM + 8192;
    ushortT* V0 = SMEM + 16384;
    ushortT* V1 = SMEM + 24576;

    // ---- Q fragments (B-op: n = q = l31, k = d = ds*16 + hi5*8 + j) ----
    // scale = 1/8 * log2(e) folded in (exp2 domain)
    const float qscale = 0.125f * 1.4426950408889634f;
    FragU Qh[4], Ql[4];
    {
        const int qrow = qs0 + l31;
#pragma unroll
        for (int ds = 0; ds < 4; ds++) {
            const float* p0 = q + base + (size_t)qrow * DIM + ds * 16 + hi5 * 8;
            float4 a = *(const float4*)(p0);
            float4 c = *(const float4*)(p0 + 4);
            float e[8] = {a.x, a.y, a.z, a.w, c.x, c.y, c.z, c.w};
#pragma unroll
            for (int j = 0; j < 8; j++) {
                float x = e[j] * qscale;
                unsigned short hs = f2bf(x);
                Qh[ds].us[j] = hs;
                Ql[ds].us[j] = f2bf(x - bf2f(hs));
            }
        }
    }

    // O^T accumulators: tile dt covers d = dt*32 + row, col q = l31
    float16v Oacc[2];
#pragma unroll
    for (int dt = 0; dt < 2; dt++)
        Oacc[dt] = (float16v){0.f,0.f,0.f,0.f,0.f,0.f,0.f,0.f,
                              0.f,0.f,0.f,0.f,0.f,0.f,0.f,0.f};

    float m_run = -INFINITY;
    float l_run = 0.f;

    auto stage_K = [&](int t, ushortT* dst) {
        const size_t tb = (size_t)(bh * 32 + t) * 4096;
        gld_lds16(KhG + tb + sl0 * 8, &dst[sl0 * 8]);
        gld_lds16(KhG + tb + sl1 * 8, &dst[sl1 * 8]);
        gld_lds16(KlG + tb + sl0 * 8, &dst[4096 + sl0 * 8]);
        gld_lds16(KlG + tb + sl1 * 8, &dst[4096 + sl1 * 8]);
    };
    auto stage_V = [&](int t, ushortT* dst) {
        const size_t tb = (size_t)(bh * 32 + t) * 4096;
        gld_lds16(VhG + tb + sl0 * 8, &dst[sl0 * 8]);
        gld_lds16(VhG + tb + sl1 * 8, &dst[sl1 * 8]);
        gld_lds16(VlG + tb + sl0 * 8, &dst[4096 + sl0 * 8]);
        gld_lds16(VlG + tb + sl1 * 8, &dst[4096 + sl1 * 8]);
    };

    // QK: S^T tile pair from K buffer Kb; C row = kv_local = (reg&3)+8*(reg>>2)+4*hi5
    // (+kvt*32), col = q = l31
    auto qk = [&](const ushortT* Kb, float16v (&st)[2]) {
        const ushortT* KhS = Kb;
        const ushortT* KlS = Kb + 4096;
#pragma unroll
        for (int t = 0; t < 2; t++)
            st[t] = (float16v){0.f,0.f,0.f,0.f,0.f,0.f,0.f,0.f,
                               0.f,0.f,0.f,0.f,0.f,0.f,0.f,0.f};
#pragma unroll
        for (int ds = 0; ds < 4; ds++) {
            FragU kh0, kl0, kh1, kl1;
            kh0.v = *(const short8v*)&KhS[(ds * 2 + 0) * 512 + lane8];
            kl0.v = *(const short8v*)&KlS[(ds * 2 + 0) * 512 + lane8];
            kh1.v = *(const short8v*)&KhS[(ds * 2 + 1) * 512 + lane8];
            kl1.v = *(const short8v*)&KlS[(ds * 2 + 1) * 512 + lane8];
            __builtin_amdgcn_s_setprio(1);
            st[0] = __builtin_amdgcn_mfma_f32_32x32x16_bf16(kh0.v, Qh[ds].v, st[0], 0, 0, 0);
            st[0] = __builtin_amdgcn_mfma_f32_32x32x16_bf16(kh0.v, Ql[ds].v, st[0], 0, 0, 0);
            st[0] = __builtin_amdgcn_mfma_f32_32x32x16_bf16(kl0.v, Qh[ds].v, st[0], 0, 0, 0);
            st[1] = __builtin_amdgcn_mfma_f32_32x32x16_bf16(kh1.v, Qh[ds].v, st[1], 0, 0, 0);
            st[1] = __builtin_amdgcn_mfma_f32_32x32x16_bf16(kh1.v, Ql[ds].v, st[1], 0, 0, 0);
            st[1] = __builtin_amdgcn_mfma_f32_32x32x16_bf16(kl1.v, Qh[ds].v, st[1], 0, 0, 0);
            __builtin_amdgcn_s_setprio(0);
        }
    };

    // softmax stats + P-pack + PV for tile in st, V from Vb. Round-3 math verbatim.
    auto finish = [&](float16v (&st)[2], const ushortT* Vb) {
        const ushortT* VhS = Vb;
        const ushortT* VlS = Vb + 4096;
        float oscale, inv;
        {
            float g[8];
#pragma unroll
            for (int t = 0; t < 2; t++)
#pragma unroll
                for (int i = 0; i < 4; i++)
                    g[t * 4 + i] = fmaxf(fmaxf(st[t][4 * i], st[t][4 * i + 1]),
                                         fmaxf(st[t][4 * i + 2], st[t][4 * i + 3]));
            float vmax = fmaxf(fmaxf(fmaxf(g[0], g[1]), fmaxf(g[2], g[3])),
                               fmaxf(fmaxf(g[4], g[5]), fmaxf(g[6], g[7])));
            vmax = fmaxf(vmax, __shfl_xor(vmax, 32, 64));
            const float mn = fmaxf(m_run, vmax);
            const float al = __builtin_amdgcn_exp2f(m_run - mn);   // 0 on first iter

            float ssum = 0.f;
#pragma unroll
            for (int t = 0; t < 2; t++)
#pragma unroll
                for (int r = 0; r < 16; r++) {
                    const float p = __builtin_amdgcn_exp2f(st[t][r] - mn);
                    st[t][r] = p;
                    ssum += p;
                }
            ssum += __shfl_xor(ssum, 32, 64);
            const float ln = al * l_run + ssum;
            inv = __builtin_amdgcn_rcpf(ln);
            oscale = al * inv;
            // fold the per-step division into P
#pragma unroll
            for (int t = 0; t < 2; t++)
#pragma unroll
                for (int r = 0; r < 16; r++)
                    st[t][r] *= inv;
            m_run = mn;
            l_run = ln;
        }

#pragma unroll
        for (int dt = 0; dt < 2; dt++)
#pragma unroll
            for (int r = 0; r < 16; r++)
                Oacc[dt][r] *= oscale;

#pragma unroll
        for (int kvs = 0; kvs < 4; kvs++) {
            const int kvt = kvs >> 1;
            const int R = (kvs & 1) * 8;
            // B-frag slice kvs needs P'[kv = kvs*16 + hi5_t*8 + j][q = l31_t]:
            //   lane-low  w0=(R0,R1)@lo w1=(R2,R3)@lo w2=(R0,R1)@hi w3=(R2,R3)@hi
            //   lane-high w0=(R4,R5)@lo w1=(R6,R7)@lo w2=(R4,R5)@hi w3=(R6,R7)@hi
            float p0 = st[kvt][R + 0], p1 = st[kvt][R + 1];
            float p2 = st[kvt][R + 2], p3 = st[kvt][R + 3];
            float p4 = st[kvt][R + 4], p5 = st[kvt][R + 5];
            float p6 = st[kvt][R + 6], p7 = st[kvt][R + 7];
            unsigned X0 = cvt_pk_bf16(p0, p1), X1 = cvt_pk_bf16(p2, p3);
            unsigned Y0 = cvt_pk_bf16(p4, p5), Y1 = cvt_pk_bf16(p6, p7);
            float e0 = p0 - __builtin_bit_cast(float, X0 << 16);
            float e1 = p1 - __builtin_bit_cast(float, X0 & 0xffff0000u);
            float e2 = p2 - __builtin_bit_cast(float, X1 << 16);
            float e3 = p3 - __builtin_bit_cast(float, X1 & 0xffff0000u);
            float e4 = p4 - __builtin_bit_cast(float, Y0 << 16);
            float e5 = p5 - __builtin_bit_cast(float, Y0 & 0xffff0000u);
            float e6 = p6 - __builtin_bit_cast(float, Y1 << 16);
            float e7 = p7 - __builtin_bit_cast(float, Y1 & 0xffff0000u);
            unsigned Z0 = cvt_pk_bf16(e0, e1), Z1 = cvt_pk_bf16(e2, e3);
            unsigned W0 = cvt_pk_bf16(e4, e5), W1 = cvt_pk_bf16(e6, e7);
            permlane32_swap(X0, Y0);
            permlane32_swap(X1, Y1);
            permlane32_swap(Z0, W0);
            permlane32_swap(Z1, W1);
            FragU Phf, Plf;
            Phf.u[0] = X0; Phf.u[1] = X1; Phf.u[2] = Y0; Phf.u[3] = Y1;
            Plf.u[0] = Z0; Plf.u[1] = Z1; Plf.u[2] = W0; Plf.u[3] = W1;

            FragU vh0, vl0, vh1, vl1;
            vh0.v = *(const short8v*)&VhS[(0 * 4 + kvs) * 512 + lane8];
            vl0.v = *(const short8v*)&VlS[(0 * 4 + kvs) * 512 + lane8];
            vh1.v = *(const short8v*)&VhS[(1 * 4 + kvs) * 512 + lane8];
            vl1.v = *(const short8v*)&VlS[(1 * 4 + kvs) * 512 + lane8];
            __builtin_amdgcn_s_setprio(1);
            Oacc[0] = __builtin_amdgcn_mfma_f32_32x32x16_bf16(vh0.v, Phf.v, Oacc[0], 0, 0, 0);
            Oacc[0] = __builtin_amdgcn_mfma_f32_32x32x16_bf16(vl0.v, Phf.v, Oacc[0], 0, 0, 0);
            Oacc[0] = __builtin_amdgcn_mfma_f32_32x32x16_bf16(vh0.v, Plf.v, Oacc[0], 0, 0, 0);
            Oacc[1] = __builtin_amdgcn_mfma_f32_32x32x16_bf16(vh1.v, Phf.v, Oacc[1], 0, 0, 0);
            Oacc[1] = __builtin_amdgcn_mfma_f32_32x32x16_bf16(vl1.v, Phf.v, Oacc[1], 0, 0, 0);
            Oacc[1] = __builtin_amdgcn_mfma_f32_32x32x16_bf16(vh1.v, Plf.v, Oacc[1], 0, 0, 0);
            __builtin_amdgcn_s_setprio(0);
        }
    };

    float16v stA[2], stB[2];

    // ---- prologue: publish K(0), K(1), V(0); compute S(0) ----
    stage_K(0, K0);
    stage_K(1, K1);
    stage_V(0, V0);
    __syncthreads();                 // vmcnt drain + publish K0,K1,V0
    qk(K0, stA);
    __syncthreads();                 // all waves done reading K0 (free for K(2))

    // ---- pipelined main loop: iteration jb works on S(jb)=SC, builds S(jb+1)=SN.
    // stage_K(jb+2 -> Kc): Kc's K(jb) consumed in iter jb-1 (pre-barrier)  [WAR ok]
    // stage_V(jb+1 -> Vn): Vn's V(jb-1) consumed in iter jb-1 (pre-barrier) [WAR ok]
    // both published by this iter's end barrier, consumed next iter        [RAW ok]
    auto iter = [&](int jb, float16v (&SC)[2], float16v (&SN)[2],
                    ushortT* Kc, ushortT* Kn, ushortT* Vc, ushortT* Vn) {
        if (jb <= 29) stage_K(jb + 2, Kc);
        if (jb <= 30) stage_V(jb + 1, Vn);
        if (jb <= 30) qk(Kn, SN);    // MFMA on jb+1 — overlaps finish(jb)'s VALU
        finish(SC, Vc);              // stats+pack (VALU) + PV (MFMA) for jb
        __syncthreads();             // drains vmcnt; publishes K(jb+2), V(jb+1)
    };

    for (int jb = 0; jb < 32; jb += 2) {
        iter(jb,     stA, stB, K0, K1, V0, V1);
        iter(jb + 1, stB, stA, K1, K0, V1, V0);
    }

    // ---- epilogue: transpose O^T per tile via wave-local LDS (reuse SMEM),
    //      split-bf16 coalesced store ----
    float* EP = ((float*)SMEM) + wave * 1056;   // [32 q][33 f32] per wave
    const int qq = lane >> 1, dh = (lane & 1) * 16;
#pragma unroll
    for (int dt = 0; dt < 2; dt++) {
#pragma unroll
        for (int g = 0; g < 4; g++) {
            // regs 4g..4g+3 -> d_local = 8g + 4*hi5 + 0..3, col q = l31
            float4 wv = make_float4(Oacc[dt][4 * g + 0], Oacc[dt][4 * g + 1],
                                    Oacc[dt][4 * g + 2], Oacc[dt][4 * g + 3]);
            *(float4*)&EP[l31 * 33 + g * 8 + hi5 * 4] = wv;
        }
        // wave-local region: lgkmcnt orders write->read, no barrier
        float vals[16];
#pragma unroll
        for (int k4 = 0; k4 < 4; k4++)
            *(float4*)&vals[k4 * 4] = *(const float4*)&EP[qq * 33 + dh + k4 * 4];

        unsigned ho[8], lo8[8];
#pragma unroll
        for (int kk = 0; kk < 8; kk++) {
            unsigned short h0, l0, h1, l1;
            split_tr(vals[2 * kk], h0, l0);
            split_tr(vals[2 * kk + 1], h1, l1);
            ho[kk]  = (unsigned)h0 | ((unsigned)h1 << 16);
            lo8[kk] = (unsigned)l0 | ((unsigned)l1 << 16);
        }
        const int qrow = qs0 + qq;
        const size_t off = (size_t)(b * SS + qrow) * DIM + h * HD + dt * 32 + dh;
        *(uint4*)&Oh[off]     = make_uint4(ho[0], ho[1], ho[2], ho[3]);
        *(uint4*)&Oh[off + 8] = make_uint4(ho[4], ho[5], ho[6], ho[7]);
        *(uint4*)&Ol[off]     = make_uint4(lo8[0], lo8[1], lo8[2], lo8[3]);
        *(uint4*)&Ol[off + 8] = make_uint4(lo8[4], lo8[5], lo8[6], lo8[7]);
    }
}

// ---------------------------------------------------------------------------
extern "C" void kernel_launch(void* const* d_in, const int* in_sizes, int n_in,
                              void* d_out, int out_size, void* d_ws, size_t ws_size,
                              hipStream_t stream)
{
    const float* x  = (const float*)d_in[0];
    const float* Wq = (const float*)d_in[1];
    const float* Wk = (const float*)d_in[2];
    const float* Wv = (const float*)d_in[3];
    const float* Wo = (const float*)d_in[4];
    float* out = (float*)d_out;

    char* w = (char*)d_ws;
    float*   qw  = (float*)(w);                        // 16 MB
    float*   kw  = (float*)(w + ((size_t)16 << 20));   // 16 MB (Oh region for attn)
    ushortT* VhG = (ushortT*)(w + ((size_t)32 << 20)); // 8 MB (V frag tiles, from GEMM)
    ushortT* VlG = (ushortT*)(w + ((size_t)40 << 20)); // 8 MB
    ushortT* XhS = (ushortT*)(w + ((size_t)48 << 20)); // 8 MB
    ushortT* XlS = (ushortT*)(w + ((size_t)56 << 20)); // 8 MB
    ushortT* WtH = (ushortT*)(w + ((size_t)64 << 20)); // 8 MB (4 matrices)
    ushortT* WtL = (ushortT*)(w + ((size_t)72 << 20)); // 8 MB
    ushortT* KhG = (ushortT*)(w + ((size_t)80 << 20)); // 8 MB (K frag tiles, from GEMM)
    ushortT* KlG = (ushortT*)(w + ((size_t)88 << 20)); // 8 MB  -> 96 MB total
    ushortT* OhS = (ushortT*)kw;
    ushortT* OlS = (ushortT*)(w + ((size_t)24 << 20));

    dim3 blk(256);
    const int n4 = MTOT * DIM / 4;

    // split X -> bf16 hi/lo; transpose+split all four W
    convert_split_kernel<<<dim3(n4 / 256), blk, 0, stream>>>(x, XhS, XlS, n4);
    transpose_split_kernel<<<dim3(16, 16, 4), blk, 0, stream>>>(Wq, Wk, Wv, Wo, WtH, WtL);

    // Q/K/V projections; z==1 (K) and z==2 (V) emit frag-major split tiles directly
    gemm_bt_split_kernel<<<dim3(8, 32, 3), blk, 0, stream>>>(
        XhS, XlS, WtH, WtL, qw, nullptr, VhG, VlG, KhG, KlG);

    // attention (exact reference recurrence, kv block = 64)
    attn_mfma_kernel<<<dim3(16, 32), blk, 0, stream>>>(qw, KhG, KlG, VhG, VlG, OhS, OlS);

    // output projection (z=0 path, fp32 out)
    gemm_bt_split_kernel<<<dim3(8, 32, 1), blk, 0, stream>>>(
        OhS, OlS, WtH + (size_t)3 * 1024 * 1024, WtL + (size_t)3 * 1024 * 1024,
        out, nullptr, nullptr, nullptr, nullptr, nullptr);
}

// Round 6
// 330.342 us; speedup vs baseline: 1.0187x; 1.0187x over previous
//
#include <hip/hip_runtime.h>
#include <hip/hip_bf16.h>
#include <math.h>

#define BB   2
#define SS   2048
#define DIM  1024
#define NH   16
#define HD   64
#define MTOT (BB * SS)   // 4096

typedef unsigned short ushortT;
typedef __attribute__((ext_vector_type(8))) short short8v;   // 8 bf16 (4 VGPRs)
typedef __attribute__((ext_vector_type(4))) float float4v;   // 4 fp32 acc
typedef __attribute__((ext_vector_type(16))) float float16v; // 16 fp32 acc (32x32 MFMA)

union FragU { short8v v; unsigned short us[8]; unsigned int u[4]; };

__device__ inline unsigned short f2bf(float x) {             // fp32 -> bf16 RNE
    unsigned u = __builtin_bit_cast(unsigned, x);
    u += 0x7fffu + ((u >> 16) & 1u);
    return (unsigned short)(u >> 16);
}
__device__ inline float bf2f(unsigned short h) {
    unsigned u = ((unsigned)h) << 16;
    return __builtin_bit_cast(float, u);
}
// truncation split: hi = trunc-to-bf16(x), lo = trunc-to-bf16(x - hi)
__device__ inline void split_tr(float x, unsigned short& hi, unsigned short& lo) {
    unsigned u = __builtin_bit_cast(unsigned, x);
    hi = (unsigned short)(u >> 16);
    float hf = __builtin_bit_cast(float, u & 0xffff0000u);
    lo = (unsigned short)(__builtin_bit_cast(unsigned, x - hf) >> 16);
}
__device__ inline void split4(const float4& x, short4& hi, short4& lo) {
    unsigned short h0 = f2bf(x.x), h1 = f2bf(x.y), h2 = f2bf(x.z), h3 = f2bf(x.w);
    hi = make_short4((short)h0, (short)h1, (short)h2, (short)h3);
    lo = make_short4((short)f2bf(x.x - bf2f(h0)), (short)f2bf(x.y - bf2f(h1)),
                     (short)f2bf(x.z - bf2f(h2)), (short)f2bf(x.w - bf2f(h3)));
}
// async global->LDS, 16 B per lane (dest = wave-uniform base + lane*16)
__device__ inline void gld_lds16(const void* g, void* l) {
    __builtin_amdgcn_global_load_lds(
        (const __attribute__((address_space(1))) void*)g,
        (__attribute__((address_space(3))) void*)l, 16, 0, 0);
}
// packed RNE bf16 convert: lo16 = bf16(a), hi16 = bf16(b)
__device__ inline unsigned cvt_pk_bf16(float a, float b) {
    unsigned r;
    asm("v_cvt_pk_bf16_f32 %0, %1, %2" : "=v"(r) : "v"(a), "v"(b));
    return r;
}
// v_permlane32_swap_b32: a' = [a(0:31), b(0:31)], b' = [a(32:63), b(32:63)]
__device__ inline void permlane32_swap(unsigned &a, unsigned &b) {
    asm("v_permlane32_swap_b32 %0, %1" : "+v"(a), "+v"(b));
}

// ---------------------------------------------------------------------------
// fp32 -> bf16 hi/lo elementwise split (X)
// ---------------------------------------------------------------------------
__global__ __launch_bounds__(256) void convert_split_kernel(
    const float* __restrict__ in, ushortT* __restrict__ hi, ushortT* __restrict__ lo, int n4)
{
    int t = blockIdx.x * 256 + threadIdx.x;
    if (t < n4) {
        float4 x = ((const float4*)in)[t];
        short4 h, l; split4(x, h, l);
        ((short4*)hi)[t] = h;
        ((short4*)lo)[t] = l;
    }
}

// ---------------------------------------------------------------------------
// W (1024x1024 fp32, K-major) -> W^T (bf16 hi/lo, N-major rows of K)
// ---------------------------------------------------------------------------
__global__ __launch_bounds__(256) void transpose_split_kernel(
    const float* __restrict__ W0, const float* __restrict__ W1,
    const float* __restrict__ W2, const float* __restrict__ W3,
    ushortT* __restrict__ WtH, ushortT* __restrict__ WtL)
{
    const int z = blockIdx.z;
    const float* __restrict__ W = (z == 0) ? W0 : (z == 1) ? W1 : (z == 2) ? W2 : W3;
    ushortT* H = WtH + (size_t)z * 1024 * 1024;
    ushortT* L = WtL + (size_t)z * 1024 * 1024;

    __shared__ float T[64][65];
    const int k0 = blockIdx.y * 64, n0 = blockIdx.x * 64;
    const int tid = threadIdx.x;
    const int c4 = (tid & 15) * 4;

#pragma unroll
    for (int i = 0; i < 4; i++) {
        int r = (tid >> 4) + 16 * i;
        *(float4*)&T[r][c4] = *(const float4*)(W + (size_t)(k0 + r) * 1024 + n0 + c4);
    }
    __syncthreads();
#pragma unroll
    for (int i = 0; i < 4; i++) {
        int n = (tid >> 4) + 16 * i;
        float4 vv = make_float4(T[c4 + 0][n], T[c4 + 1][n], T[c4 + 2][n], T[c4 + 3][n]);
        short4 h, l; split4(vv, h, l);
        *(short4*)&H[(size_t)(n0 + n) * 1024 + k0 + c4] = h;
        *(short4*)&L[(size_t)(n0 + n) * 1024 + k0 + c4] = l;
    }
}

// ---------------------------------------------------------------------------
// Split-bf16 MFMA GEMM.
//  z==2 (V projection): stores output DIRECTLY as split-bf16 frag-major
//        32x32x16 V^T A-op tiles (layout verified rounds 1-5).
//  z==1 (K projection): stores output directly as split-bf16 frag-major
//        32x32x16 K A-op tiles via per-wave LDS-bounce transpose (layout
//        verified round 5). Round-6 fix: the bounce buffer ALIASES the dead
//        staging LDS (union, 34816 B total) instead of adding 34.8 KB — the
//        round-5 regression was the 66 KB LDS cutting GEMM occupancy.
//  z==0: fp32 rows (Q projection / output projection).
// launch_bounds (256,2): 2 blocks/CU min — (256,3) cost ~18 µs via L2
// pressure; reverted.
// ---------------------------------------------------------------------------
__global__ __launch_bounds__(256, 2) void gemm_bt_split_kernel(
    const ushortT* __restrict__ Ah, const ushortT* __restrict__ Al,
    const ushortT* __restrict__ BtH, const ushortT* __restrict__ BtL,
    float* __restrict__ Y0, float* __restrict__ Y1,
    ushortT* __restrict__ VhG, ushortT* __restrict__ VlG,
    ushortT* __restrict__ KhGp, ushortT* __restrict__ KlGp)
{
    const int z = blockIdx.z;
    const ushortT* __restrict__ Bh = BtH + (size_t)z * 1024 * 1024;
    const ushortT* __restrict__ Bl = BtL + (size_t)z * 1024 * 1024;

    const int K = 1024, N = 1024;
    const int m0 = blockIdx.y * 128;
    const int n0 = blockIdx.x * 128;

    // union: staging (4 x 8192 B = 32768 B) / K-epilogue bounce (34816 B)
    __shared__ __align__(16) char SMEM_ALL[34816];
    ushortT* AhS = (ushortT*)SMEM_ALL;
    ushortT* AlS = AhS + 4096;
    ushortT* BhS = AhS + 8192;
    ushortT* BlS = AhS + 12288;

    const int tid  = threadIdx.x;
    const int wave = tid >> 6, lane = tid & 63;
    const int quad = lane >> 4, l15 = lane & 15;
    const int l31 = lane & 31, hi5g = lane >> 5;
    const int wm = wave >> 1, wn = wave & 1;

    const int s0 = tid, s1 = tid + 256;
    const int ar0 = s0 >> 2, ak0 = (s0 & 3) * 8;
    const int ar1 = s1 >> 2, ak1 = (s1 & 3) * 8;

    float4v acc[4][4];
#pragma unroll
    for (int i = 0; i < 4; i++)
#pragma unroll
        for (int j = 0; j < 4; j++) acc[i][j] = (float4v){0.f, 0.f, 0.f, 0.f};

    for (int k0 = 0; k0 < K; k0 += 32) {
        __syncthreads();
        gld_lds16(Ah + (size_t)(m0 + ar0) * K + k0 + ak0, &AhS[s0 * 8]);
        gld_lds16(Ah + (size_t)(m0 + ar1) * K + k0 + ak1, &AhS[s1 * 8]);
        gld_lds16(Al + (size_t)(m0 + ar0) * K + k0 + ak0, &AlS[s0 * 8]);
        gld_lds16(Al + (size_t)(m0 + ar1) * K + k0 + ak1, &AlS[s1 * 8]);
        gld_lds16(Bh + (size_t)(n0 + ar0) * K + k0 + ak0, &BhS[s0 * 8]);
        gld_lds16(Bh + (size_t)(n0 + ar1) * K + k0 + ak1, &BhS[s1 * 8]);
        gld_lds16(Bl + (size_t)(n0 + ar0) * K + k0 + ak0, &BlS[s0 * 8]);
        gld_lds16(Bl + (size_t)(n0 + ar1) * K + k0 + ak1, &BlS[s1 * 8]);
        __syncthreads();

        FragU ah[4], al[4], bh[4], bl[4];
#pragma unroll
        for (int t = 0; t < 4; t++) {
            ah[t].v = *(const short8v*)&AhS[(wm * 64 + t * 16 + l15) * 32 + quad * 8];
            al[t].v = *(const short8v*)&AlS[(wm * 64 + t * 16 + l15) * 32 + quad * 8];
            bh[t].v = *(const short8v*)&BhS[(wn * 64 + t * 16 + l15) * 32 + quad * 8];
            bl[t].v = *(const short8v*)&BlS[(wn * 64 + t * 16 + l15) * 32 + quad * 8];
        }
#pragma unroll
        for (int mt = 0; mt < 4; mt++)
#pragma unroll
            for (int nt = 0; nt < 4; nt++) {
                acc[mt][nt] = __builtin_amdgcn_mfma_f32_16x16x32_bf16(ah[mt].v, bh[nt].v, acc[mt][nt], 0, 0, 0);
                acc[mt][nt] = __builtin_amdgcn_mfma_f32_16x16x32_bf16(ah[mt].v, bl[nt].v, acc[mt][nt], 0, 0, 0);
                acc[mt][nt] = __builtin_amdgcn_mfma_f32_16x16x32_bf16(al[mt].v, bh[nt].v, acc[mt][nt], 0, 0, 0);
            }
    }

    if (z == 2) {
        // ---- V epilogue: direct frag-major split-bf16 V^T A-op tile store ----
        // acc element: (kv_local = mt*16 + quad*4 + r, d_local = nt*16 + l15)
        // target frag f = (nt>>1)*4 + mt, lane_t = (quad>>1)*32 + (nt&1)*16 + l15,
        // j = (quad&1)*4 + r  -> r-consecutive
        const int b  = m0 >> 11;
        const int jb = ((m0 & 2047) >> 6) + wm;
        const int h  = (n0 >> 6) + wn;
        const size_t tb = (size_t)((b * 16 + h) * 32 + jb) * 4096;
        ushortT* vh = VhG + tb;
        ushortT* vl = VlG + tb;
#pragma unroll
        for (int mt = 0; mt < 4; mt++)
#pragma unroll
            for (int nt = 0; nt < 4; nt++) {
                const int off = ((((nt >> 1) * 4 + mt) * 64 +
                                  (quad >> 1) * 32 + (nt & 1) * 16 + l15) * 8) +
                                (quad & 1) * 4;
                float4 vv = make_float4(acc[mt][nt][0], acc[mt][nt][1],
                                        acc[mt][nt][2], acc[mt][nt][3]);
                unsigned short h0, l0, h1, l1, h2, l2, h3, l3;
                split_tr(vv.x, h0, l0); split_tr(vv.y, h1, l1);
                split_tr(vv.z, h2, l2); split_tr(vv.w, h3, l3);
                *(short4*)&vh[off] = make_short4((short)h0, (short)h1, (short)h2, (short)h3);
                *(short4*)&vl[off] = make_short4((short)l0, (short)l1, (short)l2, (short)l3);
            }
    } else if (z == 1 && KhGp != nullptr) {
        // ---- K epilogue: LDS-bounce transpose to K A-op frag tiles ----
        // K A-op frag layout (= attn's): frag f = ds*2 + kvt,
        //   element (kv = kvt*32 + (lane&31), d = ds*16 + (lane>>5)*8 + j).
        // acc holds (kv_l = mt*16+quad*4+r, d_l = nt*16+l15).
        // Bounce buffer ALIASES staging LDS — barrier first (WAR vs other
        // waves' pending staging ds_reads).
        __syncthreads();
        const int b  = m0 >> 11;
        const int jb = ((m0 & 2047) >> 6) + wm;
        const int h  = (n0 >> 6) + wn;
        const size_t tb = (size_t)((b * 16 + h) * 32 + jb) * 4096;
        float* EP = ((float*)SMEM_ALL) + wave * (32 * 68);   // per-wave [32][68]
#pragma unroll
        for (int kvt = 0; kvt < 2; kvt++) {
            // write this wave's half-tile (32 kv x 64 d) to wave-local LDS
#pragma unroll
            for (int mh = 0; mh < 2; mh++) {
                const int mt = kvt * 2 + mh;
#pragma unroll
                for (int nt = 0; nt < 4; nt++)
#pragma unroll
                    for (int r = 0; r < 4; r++)
                        EP[(mh * 16 + quad * 4 + r) * 68 + nt * 16 + l15] = acc[mt][nt][r];
            }
            // wave-local region: lgkmcnt orders write->read, no barrier
#pragma unroll
            for (int ds = 0; ds < 4; ds++) {
                const int d0 = ds * 16 + hi5g * 8;
                float4 va = *(const float4*)&EP[l31 * 68 + d0];
                float4 vb = *(const float4*)&EP[l31 * 68 + d0 + 4];
                float ev[8] = {va.x, va.y, va.z, va.w, vb.x, vb.y, vb.z, vb.w};
                ushortT hv[8], lv[8];
#pragma unroll
                for (int j = 0; j < 8; j++) split_tr(ev[j], hv[j], lv[j]);
                const size_t o8 = tb + (size_t)(ds * 2 + kvt) * 512 + lane * 8;
                *(short4*)&KhGp[o8]     = *(short4*)&hv[0];
                *(short4*)&KhGp[o8 + 4] = *(short4*)&hv[4];
                *(short4*)&KlGp[o8]     = *(short4*)&lv[0];
                *(short4*)&KlGp[o8 + 4] = *(short4*)&lv[4];
            }
        }
    } else {
        float* __restrict__ Y = (z == 0) ? Y0 : Y1;
#pragma unroll
        for (int mt = 0; mt < 4; mt++)
#pragma unroll
            for (int r = 0; r < 4; r++) {
                const int row = m0 + wm * 64 + mt * 16 + quad * 4 + r;
                float* yp = Y + (size_t)row * N + n0 + wn * 64 + l15;
#pragma unroll
                for (int nt = 0; nt < 4; nt++)
                    yp[nt * 16] = acc[mt][nt][r];
            }
    }
}

// ---------------------------------------------------------------------------
// MFMA attention, 32x32x16. Round-6 = round-4 verbatim (best: 113.6 µs).
// Software pipeline: QK(jb+1) issued before finish(jb); K 2-ahead, V 1-ahead;
// one barrier per iter. NO setprio (round-5: T5 cost 2.9 µs on this
// barrier-synced structure — m190-consistent).
// Math: exact reference recurrence O = (alpha*O + P@V)/l_new EVERY kv step
// (per-step division is SEMANTIC, does not telescope — round-2 lesson).
// ---------------------------------------------------------------------------
__global__ __launch_bounds__(256, 2) void attn_mfma_kernel(
    const float* __restrict__ q,
    const ushortT* __restrict__ KhG, const ushortT* __restrict__ KlG,
    const ushortT* __restrict__ VhG, const ushortT* __restrict__ VlG,
    ushortT* __restrict__ Oh, ushortT* __restrict__ Ol)
{
    // layout (ushort units): K0 @0, K1 @8192, V0 @16384, V1 @24576
    // each Kx/Vx = {hi 4096, lo 4096}
    __shared__ __align__(16) ushortT SMEM[32768];   // 64 KiB

    const int tid  = threadIdx.x;
    const int wave = tid >> 6, lane = tid & 63;
    const int l31 = lane & 31, hi5 = lane >> 5;
    const int bh = blockIdx.y, b = bh >> 4, h = bh & 15;
    const size_t base = (size_t)b * SS * DIM + (size_t)h * HD;
    const int qs0 = blockIdx.x * 128 + wave * 32;
    const int lane8 = lane * 8;
    const int sl0 = wave * 128 + lane, sl1 = sl0 + 64;

    ushortT* K0 = SMEM;
    ushortT* K1 = SMEM + 8192;
    ushortT* V0 = SMEM + 16384;
    ushortT* V1 = SMEM + 24576;

    // ---- Q fragments (B-op: n = q = l31, k = d = ds*16 + hi5*8 + j) ----
    // scale = 1/8 * log2(e) folded in (exp2 domain)
    const float qscale = 0.125f * 1.4426950408889634f;
    FragU Qh[4], Ql[4];
    {
        const int qrow = qs0 + l31;
#pragma unroll
        for (int ds = 0; ds < 4; ds++) {
            const float* p0 = q + base + (size_t)qrow * DIM + ds * 16 + hi5 * 8;
            float4 a = *(const float4*)(p0);
            float4 c = *(const float4*)(p0 + 4);
            float e[8] = {a.x, a.y, a.z, a.w, c.x, c.y, c.z, c.w};
#pragma unroll
            for (int j = 0; j < 8; j++) {
                float x = e[j] * qscale;
                unsigned short hs = f2bf(x);
                Qh[ds].us[j] = hs;
                Ql[ds].us[j] = f2bf(x - bf2f(hs));
            }
        }
    }

    // O^T accumulators: tile dt covers d = dt*32 + row, col q = l31
    float16v Oacc[2];
#pragma unroll
    for (int dt = 0; dt < 2; dt++)
        Oacc[dt] = (float16v){0.f,0.f,0.f,0.f,0.f,0.f,0.f,0.f,
                              0.f,0.f,0.f,0.f,0.f,0.f,0.f,0.f};

    float m_run = -INFINITY;
    float l_run = 0.f;

    auto stage_K = [&](int t, ushortT* dst) {
        const size_t tb = (size_t)(bh * 32 + t) * 4096;
        gld_lds16(KhG + tb + sl0 * 8, &dst[sl0 * 8]);
        gld_lds16(KhG + tb + sl1 * 8, &dst[sl1 * 8]);
        gld_lds16(KlG + tb + sl0 * 8, &dst[4096 + sl0 * 8]);
        gld_lds16(KlG + tb + sl1 * 8, &dst[4096 + sl1 * 8]);
    };
    auto stage_V = [&](int t, ushortT* dst) {
        const size_t tb = (size_t)(bh * 32 + t) * 4096;
        gld_lds16(VhG + tb + sl0 * 8, &dst[sl0 * 8]);
        gld_lds16(VhG + tb + sl1 * 8, &dst[sl1 * 8]);
        gld_lds16(VlG + tb + sl0 * 8, &dst[4096 + sl0 * 8]);
        gld_lds16(VlG + tb + sl1 * 8, &dst[4096 + sl1 * 8]);
    };

    // QK: S^T tile pair from K buffer Kb; C row = kv_local = (reg&3)+8*(reg>>2)+4*hi5
    // (+kvt*32), col = q = l31
    auto qk = [&](const ushortT* Kb, float16v (&st)[2]) {
        const ushortT* KhS = Kb;
        const ushortT* KlS = Kb + 4096;
#pragma unroll
        for (int t = 0; t < 2; t++)
            st[t] = (float16v){0.f,0.f,0.f,0.f,0.f,0.f,0.f,0.f,
                               0.f,0.f,0.f,0.f,0.f,0.f,0.f,0.f};
#pragma unroll
        for (int ds = 0; ds < 4; ds++) {
            FragU kh0, kl0, kh1, kl1;
            kh0.v = *(const short8v*)&KhS[(ds * 2 + 0) * 512 + lane8];
            kl0.v = *(const short8v*)&KlS[(ds * 2 + 0) * 512 + lane8];
            kh1.v = *(const short8v*)&KhS[(ds * 2 + 1) * 512 + lane8];
            kl1.v = *(const short8v*)&KlS[(ds * 2 + 1) * 512 + lane8];
            st[0] = __builtin_amdgcn_mfma_f32_32x32x16_bf16(kh0.v, Qh[ds].v, st[0], 0, 0, 0);
            st[0] = __builtin_amdgcn_mfma_f32_32x32x16_bf16(kh0.v, Ql[ds].v, st[0], 0, 0, 0);
            st[0] = __builtin_amdgcn_mfma_f32_32x32x16_bf16(kl0.v, Qh[ds].v, st[0], 0, 0, 0);
            st[1] = __builtin_amdgcn_mfma_f32_32x32x16_bf16(kh1.v, Qh[ds].v, st[1], 0, 0, 0);
            st[1] = __builtin_amdgcn_mfma_f32_32x32x16_bf16(kh1.v, Ql[ds].v, st[1], 0, 0, 0);
            st[1] = __builtin_amdgcn_mfma_f32_32x32x16_bf16(kl1.v, Qh[ds].v, st[1], 0, 0, 0);
        }
    };

    // softmax stats + P-pack + PV for tile in st, V from Vb. Round-3 math verbatim.
    auto finish = [&](float16v (&st)[2], const ushortT* Vb) {
        const ushortT* VhS = Vb;
        const ushortT* VlS = Vb + 4096;
        float oscale, inv;
        {
            float g[8];
#pragma unroll
            for (int t = 0; t < 2; t++)
#pragma unroll
                for (int i = 0; i < 4; i++)
                    g[t * 4 + i] = fmaxf(fmaxf(st[t][4 * i], st[t][4 * i + 1]),
                                         fmaxf(st[t][4 * i + 2], st[t][4 * i + 3]));
            float vmax = fmaxf(fmaxf(fmaxf(g[0], g[1]), fmaxf(g[2], g[3])),
                               fmaxf(fmaxf(g[4], g[5]), fmaxf(g[6], g[7])));
            vmax = fmaxf(vmax, __shfl_xor(vmax, 32, 64));
            const float mn = fmaxf(m_run, vmax);
            const float al = __builtin_amdgcn_exp2f(m_run - mn);   // 0 on first iter

            float ssum = 0.f;
#pragma unroll
            for (int t = 0; t < 2; t++)
#pragma unroll
                for (int r = 0; r < 16; r++) {
                    const float p = __builtin_amdgcn_exp2f(st[t][r] - mn);
                    st[t][r] = p;
                    ssum += p;
                }
            ssum += __shfl_xor(ssum, 32, 64);
            const float ln = al * l_run + ssum;
            inv = __builtin_amdgcn_rcpf(ln);
            oscale = al * inv;
            // fold the per-step division into P
#pragma unroll
            for (int t = 0; t < 2; t++)
#pragma unroll
                for (int r = 0; r < 16; r++)
                    st[t][r] *= inv;
            m_run = mn;
            l_run = ln;
        }

#pragma unroll
        for (int dt = 0; dt < 2; dt++)
#pragma unroll
            for (int r = 0; r < 16; r++)
                Oacc[dt][r] *= oscale;

#pragma unroll
        for (int kvs = 0; kvs < 4; kvs++) {
            const int kvt = kvs >> 1;
            const int R = (kvs & 1) * 8;
            // B-frag slice kvs needs P'[kv = kvs*16 + hi5_t*8 + j][q = l31_t]:
            //   lane-low  w0=(R0,R1)@lo w1=(R2,R3)@lo w2=(R0,R1)@hi w3=(R2,R3)@hi
            //   lane-high w0=(R4,R5)@lo w1=(R6,R7)@lo w2=(R4,R5)@hi w3=(R6,R7)@hi
            float p0 = st[kvt][R + 0], p1 = st[kvt][R + 1];
            float p2 = st[kvt][R + 2], p3 = st[kvt][R + 3];
            float p4 = st[kvt][R + 4], p5 = st[kvt][R + 5];
            float p6 = st[kvt][R + 6], p7 = st[kvt][R + 7];
            unsigned X0 = cvt_pk_bf16(p0, p1), X1 = cvt_pk_bf16(p2, p3);
            unsigned Y0 = cvt_pk_bf16(p4, p5), Y1 = cvt_pk_bf16(p6, p7);
            float e0 = p0 - __builtin_bit_cast(float, X0 << 16);
            float e1 = p1 - __builtin_bit_cast(float, X0 & 0xffff0000u);
            float e2 = p2 - __builtin_bit_cast(float, X1 << 16);
            float e3 = p3 - __builtin_bit_cast(float, X1 & 0xffff0000u);
            float e4 = p4 - __builtin_bit_cast(float, Y0 << 16);
            float e5 = p5 - __builtin_bit_cast(float, Y0 & 0xffff0000u);
            float e6 = p6 - __builtin_bit_cast(float, Y1 << 16);
            float e7 = p7 - __builtin_bit_cast(float, Y1 & 0xffff0000u);
            unsigned Z0 = cvt_pk_bf16(e0, e1), Z1 = cvt_pk_bf16(e2, e3);
            unsigned W0 = cvt_pk_bf16(e4, e5), W1 = cvt_pk_bf16(e6, e7);
            permlane32_swap(X0, Y0);
            permlane32_swap(X1, Y1);
            permlane32_swap(Z0, W0);
            permlane32_swap(Z1, W1);
            FragU Phf, Plf;
            Phf.u[0] = X0; Phf.u[1] = X1; Phf.u[2] = Y0; Phf.u[3] = Y1;
            Plf.u[0] = Z0; Plf.u[1] = Z1; Plf.u[2] = W0; Plf.u[3] = W1;

#pragma unroll
            for (int dt = 0; dt < 2; dt++) {
                FragU vh, vl;
                vh.v = *(const short8v*)&VhS[(dt * 4 + kvs) * 512 + lane8];
                vl.v = *(const short8v*)&VlS[(dt * 4 + kvs) * 512 + lane8];
                Oacc[dt] = __builtin_amdgcn_mfma_f32_32x32x16_bf16(vh.v, Phf.v, Oacc[dt], 0, 0, 0);
                Oacc[dt] = __builtin_amdgcn_mfma_f32_32x32x16_bf16(vl.v, Phf.v, Oacc[dt], 0, 0, 0);
                Oacc[dt] = __builtin_amdgcn_mfma_f32_32x32x16_bf16(vh.v, Plf.v, Oacc[dt], 0, 0, 0);
            }
        }
    };

    float16v stA[2], stB[2];

    // ---- prologue: publish K(0), K(1), V(0); compute S(0) ----
    stage_K(0, K0);
    stage_K(1, K1);
    stage_V(0, V0);
    __syncthreads();                 // vmcnt drain + publish K0,K1,V0
    qk(K0, stA);
    __syncthreads();                 // all waves done reading K0 (free for K(2))

    // ---- pipelined main loop: iteration jb works on S(jb)=SC, builds S(jb+1)=SN.
    // stage_K(jb+2 -> Kc): Kc's K(jb) consumed in iter jb-1 (pre-barrier)  [WAR ok]
    // stage_V(jb+1 -> Vn): Vn's V(jb-1) consumed in iter jb-1 (pre-barrier) [WAR ok]
    // both published by this iter's end barrier, consumed next iter        [RAW ok]
    auto iter = [&](int jb, float16v (&SC)[2], float16v (&SN)[2],
                    ushortT* Kc, ushortT* Kn, ushortT* Vc, ushortT* Vn) {
        if (jb <= 29) stage_K(jb + 2, Kc);
        if (jb <= 30) stage_V(jb + 1, Vn);
        if (jb <= 30) qk(Kn, SN);    // MFMA on jb+1 — overlaps finish(jb)'s VALU
        finish(SC, Vc);              // stats+pack (VALU) + PV (MFMA) for jb
        __syncthreads();             // drains vmcnt; publishes K(jb+2), V(jb+1)
    };

    for (int jb = 0; jb < 32; jb += 2) {
        iter(jb,     stA, stB, K0, K1, V0, V1);
        iter(jb + 1, stB, stA, K1, K0, V1, V0);
    }

    // ---- epilogue: transpose O^T per tile via wave-local LDS (reuse SMEM),
    //      split-bf16 coalesced store ----
    float* EP = ((float*)SMEM) + wave * 1056;   // [32 q][33 f32] per wave
    const int qq = lane >> 1, dh = (lane & 1) * 16;
#pragma unroll
    for (int dt = 0; dt < 2; dt++) {
#pragma unroll
        for (int g = 0; g < 4; g++) {
            // regs 4g..4g+3 -> d_local = 8g + 4*hi5 + 0..3, col q = l31
            float4 wv = make_float4(Oacc[dt][4 * g + 0], Oacc[dt][4 * g + 1],
                                    Oacc[dt][4 * g + 2], Oacc[dt][4 * g + 3]);
            *(float4*)&EP[l31 * 33 + g * 8 + hi5 * 4] = wv;
        }
        // wave-local region: lgkmcnt orders write->read, no barrier
        float vals[16];
#pragma unroll
        for (int k4 = 0; k4 < 4; k4++)
            *(float4*)&vals[k4 * 4] = *(const float4*)&EP[qq * 33 + dh + k4 * 4];

        unsigned ho[8], lo8[8];
#pragma unroll
        for (int kk = 0; kk < 8; kk++) {
            unsigned short h0, l0, h1, l1;
            split_tr(vals[2 * kk], h0, l0);
            split_tr(vals[2 * kk + 1], h1, l1);
            ho[kk]  = (unsigned)h0 | ((unsigned)h1 << 16);
            lo8[kk] = (unsigned)l0 | ((unsigned)l1 << 16);
        }
        const int qrow = qs0 + qq;
        const size_t off = (size_t)(b * SS + qrow) * DIM + h * HD + dt * 32 + dh;
        *(uint4*)&Oh[off]     = make_uint4(ho[0], ho[1], ho[2], ho[3]);
        *(uint4*)&Oh[off + 8] = make_uint4(ho[4], ho[5], ho[6], ho[7]);
        *(uint4*)&Ol[off]     = make_uint4(lo8[0], lo8[1], lo8[2], lo8[3]);
        *(uint4*)&Ol[off + 8] = make_uint4(lo8[4], lo8[5], lo8[6], lo8[7]);
    }
}

// ---------------------------------------------------------------------------
extern "C" void kernel_launch(void* const* d_in, const int* in_sizes, int n_in,
                              void* d_out, int out_size, void* d_ws, size_t ws_size,
                              hipStream_t stream)
{
    const float* x  = (const float*)d_in[0];
    const float* Wq = (const float*)d_in[1];
    const float* Wk = (const float*)d_in[2];
    const float* Wv = (const float*)d_in[3];
    const float* Wo = (const float*)d_in[4];
    float* out = (float*)d_out;

    char* w = (char*)d_ws;
    float*   qw  = (float*)(w);                        // 16 MB
    float*   kw  = (float*)(w + ((size_t)16 << 20));   // 16 MB (Oh region for attn)
    ushortT* VhG = (ushortT*)(w + ((size_t)32 << 20)); // 8 MB (V frag tiles, from GEMM)
    ushortT* VlG = (ushortT*)(w + ((size_t)40 << 20)); // 8 MB
    ushortT* XhS = (ushortT*)(w + ((size_t)48 << 20)); // 8 MB
    ushortT* XlS = (ushortT*)(w + ((size_t)56 << 20)); // 8 MB
    ushortT* WtH = (ushortT*)(w + ((size_t)64 << 20)); // 8 MB (4 matrices)
    ushortT* WtL = (ushortT*)(w + ((size_t)72 << 20)); // 8 MB
    ushortT* KhG = (ushortT*)(w + ((size_t)80 << 20)); // 8 MB (K frag tiles, from GEMM)
    ushortT* KlG = (ushortT*)(w + ((size_t)88 << 20)); // 8 MB  -> 96 MB total
    ushortT* OhS = (ushortT*)kw;
    ushortT* OlS = (ushortT*)(w + ((size_t)24 << 20));

    dim3 blk(256);
    const int n4 = MTOT * DIM / 4;

    // split X -> bf16 hi/lo; transpose+split all four W
    convert_split_kernel<<<dim3(n4 / 256), blk, 0, stream>>>(x, XhS, XlS, n4);
    transpose_split_kernel<<<dim3(16, 16, 4), blk, 0, stream>>>(Wq, Wk, Wv, Wo, WtH, WtL);

    // Q/K/V projections; z==1 (K) and z==2 (V) emit frag-major split tiles directly
    gemm_bt_split_kernel<<<dim3(8, 32, 3), blk, 0, stream>>>(
        XhS, XlS, WtH, WtL, qw, nullptr, VhG, VlG, KhG, KlG);

    // attention (exact reference recurrence, kv block = 64)
    attn_mfma_kernel<<<dim3(16, 32), blk, 0, stream>>>(qw, KhG, KlG, VhG, VlG, OhS, OlS);

    // output projection (z=0 path, fp32 out)
    gemm_bt_split_kernel<<<dim3(8, 32, 1), blk, 0, stream>>>(
        OhS, OlS, WtH + (size_t)3 * 1024 * 1024, WtL + (size_t)3 * 1024 * 1024,
        out, nullptr, nullptr, nullptr, nullptr, nullptr);
}

// Round 7
// 311.633 us; speedup vs baseline: 1.0799x; 1.0600x over previous
//
#include <hip/hip_runtime.h>
#include <hip/hip_bf16.h>
#include <math.h>

#define BB   2
#define SS   2048
#define DIM  1024
#define NH   16
#define HD   64
#define MTOT (BB * SS)   // 4096

typedef unsigned short ushortT;
typedef __attribute__((ext_vector_type(8))) short short8v;   // 8 bf16 (4 VGPRs)
typedef __attribute__((ext_vector_type(4))) float float4v;   // 4 fp32 acc
typedef __attribute__((ext_vector_type(16))) float float16v; // 16 fp32 acc (32x32 MFMA)

union FragU { short8v v; unsigned short us[8]; unsigned int u[4]; };

__device__ inline unsigned short f2bf(float x) {             // fp32 -> bf16 RNE
    unsigned u = __builtin_bit_cast(unsigned, x);
    u += 0x7fffu + ((u >> 16) & 1u);
    return (unsigned short)(u >> 16);
}
__device__ inline float bf2f(unsigned short h) {
    unsigned u = ((unsigned)h) << 16;
    return __builtin_bit_cast(float, u);
}
// truncation split: hi = trunc-to-bf16(x), lo = trunc-to-bf16(x - hi)
__device__ inline void split_tr(float x, unsigned short& hi, unsigned short& lo) {
    unsigned u = __builtin_bit_cast(unsigned, x);
    hi = (unsigned short)(u >> 16);
    float hf = __builtin_bit_cast(float, u & 0xffff0000u);
    lo = (unsigned short)(__builtin_bit_cast(unsigned, x - hf) >> 16);
}
__device__ inline void split4(const float4& x, short4& hi, short4& lo) {
    unsigned short h0 = f2bf(x.x), h1 = f2bf(x.y), h2 = f2bf(x.z), h3 = f2bf(x.w);
    hi = make_short4((short)h0, (short)h1, (short)h2, (short)h3);
    lo = make_short4((short)f2bf(x.x - bf2f(h0)), (short)f2bf(x.y - bf2f(h1)),
                     (short)f2bf(x.z - bf2f(h2)), (short)f2bf(x.w - bf2f(h3)));
}
// async global->LDS, 16 B per lane (dest = wave-uniform base + lane*16)
__device__ inline void gld_lds16(const void* g, void* l) {
    __builtin_amdgcn_global_load_lds(
        (const __attribute__((address_space(1))) void*)g,
        (__attribute__((address_space(3))) void*)l, 16, 0, 0);
}
// packed RNE bf16 convert: lo16 = bf16(a), hi16 = bf16(b)
__device__ inline unsigned cvt_pk_bf16(float a, float b) {
    unsigned r;
    asm("v_cvt_pk_bf16_f32 %0, %1, %2" : "=v"(r) : "v"(a), "v"(b));
    return r;
}
// v_permlane32_swap_b32: a' = [a(0:31), b(0:31)], b' = [a(32:63), b(32:63)]
__device__ inline void permlane32_swap(unsigned &a, unsigned &b) {
    asm("v_permlane32_swap_b32 %0, %1" : "+v"(a), "+v"(b));
}

// ---------------------------------------------------------------------------
// fp32 -> bf16 hi/lo elementwise split (X)
// ---------------------------------------------------------------------------
__global__ __launch_bounds__(256) void convert_split_kernel(
    const float* __restrict__ in, ushortT* __restrict__ hi, ushortT* __restrict__ lo, int n4)
{
    int t = blockIdx.x * 256 + threadIdx.x;
    if (t < n4) {
        float4 x = ((const float4*)in)[t];
        short4 h, l; split4(x, h, l);
        ((short4*)hi)[t] = h;
        ((short4*)lo)[t] = l;
    }
}

// ---------------------------------------------------------------------------
// W (1024x1024 fp32, K-major) -> W^T (bf16 hi/lo, N-major rows of K)
// ---------------------------------------------------------------------------
__global__ __launch_bounds__(256) void transpose_split_kernel(
    const float* __restrict__ W0, const float* __restrict__ W1,
    const float* __restrict__ W2, const float* __restrict__ W3,
    ushortT* __restrict__ WtH, ushortT* __restrict__ WtL)
{
    const int z = blockIdx.z;
    const float* __restrict__ W = (z == 0) ? W0 : (z == 1) ? W1 : (z == 2) ? W2 : W3;
    ushortT* H = WtH + (size_t)z * 1024 * 1024;
    ushortT* L = WtL + (size_t)z * 1024 * 1024;

    __shared__ float T[64][65];
    const int k0 = blockIdx.y * 64, n0 = blockIdx.x * 64;
    const int tid = threadIdx.x;
    const int c4 = (tid & 15) * 4;

#pragma unroll
    for (int i = 0; i < 4; i++) {
        int r = (tid >> 4) + 16 * i;
        *(float4*)&T[r][c4] = *(const float4*)(W + (size_t)(k0 + r) * 1024 + n0 + c4);
    }
    __syncthreads();
#pragma unroll
    for (int i = 0; i < 4; i++) {
        int n = (tid >> 4) + 16 * i;
        float4 vv = make_float4(T[c4 + 0][n], T[c4 + 1][n], T[c4 + 2][n], T[c4 + 3][n]);
        short4 h, l; split4(vv, h, l);
        *(short4*)&H[(size_t)(n0 + n) * 1024 + k0 + c4] = h;
        *(short4*)&L[(size_t)(n0 + n) * 1024 + k0 + c4] = l;
    }
}

// ---------------------------------------------------------------------------
// K fp32 (B,S,H*D) -> bf16 hi/lo 64x64 tiles, frag-major for 32x32x16 A-op.
// Frag f = ds*2 + kvt: element (kv = kvt*32 + (lane&31), d = ds*16 + (lane>>5)*8 + j)
// ---------------------------------------------------------------------------
__global__ __launch_bounds__(256) void kv_convert_kernel(
    const float* __restrict__ kw,
    ushortT* __restrict__ KhG, ushortT* __restrict__ KlG)
{
    const int jb = blockIdx.x, bh = blockIdx.y;
    const int b = bh >> 4, h = bh & 15;

    __shared__ float T[64][68];
    const int tid = threadIdx.x;
    const size_t ibase = (size_t)b * SS * DIM + (size_t)h * HD + (size_t)(jb * 64) * DIM;
    const int c4 = (tid & 15) * 4;
#pragma unroll
    for (int i = 0; i < 4; i++) {
        int r = (tid >> 4) + 16 * i;
        *(float4*)&T[r][c4] = *(const float4*)(kw + ibase + (size_t)r * DIM + c4);
    }
    __syncthreads();

    ushortT* oh = KhG + (size_t)(bh * 32 + jb) * 4096;
    ushortT* ol = KlG + (size_t)(bh * 32 + jb) * 4096;

#pragma unroll
    for (int i = 0; i < 2; i++) {
        const int s = tid + i * 256;          // slot 0..511
        const int f = s >> 6;                 // frag 0..7
        const int lane = s & 63;
        const int ds = f >> 1, kvt = f & 1;
        const int kv = kvt * 32 + (lane & 31);
        const int d0 = ds * 16 + (lane >> 5) * 8;
        ushortT hv[8], lv[8];
#pragma unroll
        for (int j = 0; j < 8; j++) split_tr(T[kv][d0 + j], hv[j], lv[j]);
        *(short4*)&oh[s * 8]     = *(short4*)&hv[0];
        *(short4*)&oh[s * 8 + 4] = *(short4*)&hv[4];
        *(short4*)&ol[s * 8]     = *(short4*)&lv[0];
        *(short4*)&ol[s * 8 + 4] = *(short4*)&lv[4];
    }
}

// ---------------------------------------------------------------------------
// Split-bf16 MFMA GEMM. z==2 (V projection) stores its output DIRECTLY as
// split-bf16 frag-major 32x32x16 V^T A-op tiles. z==0/1 store fp32 rows.
// Round-7: BK=64 (16 k-steps instead of 32 — halves barrier-drain count)
// + XOR-swizzled LDS (both-sides: staging source k-block ^= row&7, frag read
// block ^= l15&7) — 128B row stride would be 16-way bank-conflicted unswizzled;
// old 64B stride was already 8-way. Accumulation order bit-identical to BK=32.
// launch_bounds (256,2): 2 blocks/CU (VGPR-capped; (256,3) cost ~18 µs via
// L2 pressure — reverted). LDS 64 KB -> still 2 blocks/CU.
// Round-6 lesson: K-projection fusion into this kernel was net-negative
// (epilogue + L2 placement costs > saved 32MB round-trip); kv_convert kept.
// ---------------------------------------------------------------------------
__global__ __launch_bounds__(256, 2) void gemm_bt_split_kernel(
    const ushortT* __restrict__ Ah, const ushortT* __restrict__ Al,
    const ushortT* __restrict__ BtH, const ushortT* __restrict__ BtL,
    float* __restrict__ Y0, float* __restrict__ Y1,
    ushortT* __restrict__ VhG, ushortT* __restrict__ VlG)
{
    const int z = blockIdx.z;
    const ushortT* __restrict__ Bh = BtH + (size_t)z * 1024 * 1024;
    const ushortT* __restrict__ Bl = BtL + (size_t)z * 1024 * 1024;

    const int K = 1024, N = 1024;
    const int m0 = blockIdx.y * 128;
    const int n0 = blockIdx.x * 128;

    __shared__ __align__(16) ushortT AhS[128 * 64];
    __shared__ __align__(16) ushortT AlS[128 * 64];
    __shared__ __align__(16) ushortT BhS[128 * 64];
    __shared__ __align__(16) ushortT BlS[128 * 64];

    const int tid  = threadIdx.x;
    const int wave = tid >> 6, lane = tid & 63;
    const int quad = lane >> 4, l15 = lane & 15;
    const int wm = wave >> 1, wn = wave & 1;
    const int rx = l15 & 7;                 // read-side swizzle key

    float4v acc[4][4];
#pragma unroll
    for (int i = 0; i < 4; i++)
#pragma unroll
        for (int j = 0; j < 4; j++) acc[i][j] = (float4v){0.f, 0.f, 0.f, 0.f};

    for (int k0 = 0; k0 < K; k0 += 64) {
        __syncthreads();
#pragma unroll
        for (int i = 0; i < 4; i++) {
            const int s = tid + i * 256;    // slot 0..1023: row r = s>>3, blk = s&7
            const int r = s >> 3;
            // swizzle: LDS 16B-block (r, s&7) holds global k-block ((s&7) ^ (r&7))
            const int kk = ((s & 7) ^ (r & 7)) * 8;
            gld_lds16(Ah + (size_t)(m0 + r) * K + k0 + kk, &AhS[s * 8]);
            gld_lds16(Al + (size_t)(m0 + r) * K + k0 + kk, &AlS[s * 8]);
            gld_lds16(Bh + (size_t)(n0 + r) * K + k0 + kk, &BhS[s * 8]);
            gld_lds16(Bl + (size_t)(n0 + r) * K + k0 + kk, &BlS[s * 8]);
        }
        __syncthreads();

#pragma unroll
        for (int ks = 0; ks < 2; ks++) {
            FragU ah[4], al[4], bh[4], bl[4];
#pragma unroll
            for (int t = 0; t < 4; t++) {
                const int ra = wm * 64 + t * 16 + l15;   // ra&7 == rx
                const int rb = wn * 64 + t * 16 + l15;
                const int boff = ((ks * 4 + quad) ^ rx) * 8;
                ah[t].v = *(const short8v*)&AhS[ra * 64 + boff];
                al[t].v = *(const short8v*)&AlS[ra * 64 + boff];
                bh[t].v = *(const short8v*)&BhS[rb * 64 + boff];
                bl[t].v = *(const short8v*)&BlS[rb * 64 + boff];
            }
#pragma unroll
            for (int mt = 0; mt < 4; mt++)
#pragma unroll
                for (int nt = 0; nt < 4; nt++) {
                    acc[mt][nt] = __builtin_amdgcn_mfma_f32_16x16x32_bf16(ah[mt].v, bh[nt].v, acc[mt][nt], 0, 0, 0);
                    acc[mt][nt] = __builtin_amdgcn_mfma_f32_16x16x32_bf16(ah[mt].v, bl[nt].v, acc[mt][nt], 0, 0, 0);
                    acc[mt][nt] = __builtin_amdgcn_mfma_f32_16x16x32_bf16(al[mt].v, bh[nt].v, acc[mt][nt], 0, 0, 0);
                }
        }
    }

    if (z == 2) {
        // ---- V epilogue: direct frag-major split-bf16 V^T A-op tile store ----
        // acc element: (kv_local = mt*16 + quad*4 + r, d_local = nt*16 + l15)
        // target frag f = (nt>>1)*4 + mt, lane_t = (quad>>1)*32 + (nt&1)*16 + l15,
        // j = (quad&1)*4 + r  -> r-consecutive
        const int b  = m0 >> 11;
        const int jb = ((m0 & 2047) >> 6) + wm;
        const int h  = (n0 >> 6) + wn;
        const size_t tb = (size_t)((b * 16 + h) * 32 + jb) * 4096;
        ushortT* vh = VhG + tb;
        ushortT* vl = VlG + tb;
#pragma unroll
        for (int mt = 0; mt < 4; mt++)
#pragma unroll
            for (int nt = 0; nt < 4; nt++) {
                const int off = ((((nt >> 1) * 4 + mt) * 64 +
                                  (quad >> 1) * 32 + (nt & 1) * 16 + l15) * 8) +
                                (quad & 1) * 4;
                float4 vv = make_float4(acc[mt][nt][0], acc[mt][nt][1],
                                        acc[mt][nt][2], acc[mt][nt][3]);
                unsigned short h0, l0, h1, l1, h2, l2, h3, l3;
                split_tr(vv.x, h0, l0); split_tr(vv.y, h1, l1);
                split_tr(vv.z, h2, l2); split_tr(vv.w, h3, l3);
                *(short4*)&vh[off] = make_short4((short)h0, (short)h1, (short)h2, (short)h3);
                *(short4*)&vl[off] = make_short4((short)l0, (short)l1, (short)l2, (short)l3);
            }
    } else {
        float* __restrict__ Y = (z == 0) ? Y0 : Y1;
#pragma unroll
        for (int mt = 0; mt < 4; mt++)
#pragma unroll
            for (int r = 0; r < 4; r++) {
                const int row = m0 + wm * 64 + mt * 16 + quad * 4 + r;
                float* yp = Y + (size_t)row * N + n0 + wn * 64 + l15;
#pragma unroll
                for (int nt = 0; nt < 4; nt++)
                    yp[nt * 16] = acc[mt][nt][r];
            }
    }
}

// ---------------------------------------------------------------------------
// MFMA attention, 32x32x16. Round-7 = round-4 verbatim (best: 113.6 µs).
// Software pipeline: QK(jb+1) issued before finish(jb); K 2-ahead, V 1-ahead;
// one barrier per iter. NO setprio (round-5: T5 cost 2.9 µs on this
// barrier-synced structure — m190-consistent).
// Math: exact reference recurrence O = (alpha*O + P@V)/l_new EVERY kv step
// (per-step division is SEMANTIC, does not telescope — round-2 lesson).
// ---------------------------------------------------------------------------
__global__ __launch_bounds__(256, 2) void attn_mfma_kernel(
    const float* __restrict__ q,
    const ushortT* __restrict__ KhG, const ushortT* __restrict__ KlG,
    const ushortT* __restrict__ VhG, const ushortT* __restrict__ VlG,
    ushortT* __restrict__ Oh, ushortT* __restrict__ Ol)
{
    // layout (ushort units): K0 @0, K1 @8192, V0 @16384, V1 @24576
    // each Kx/Vx = {hi 4096, lo 4096}
    __shared__ __align__(16) ushortT SMEM[32768];   // 64 KiB

    const int tid  = threadIdx.x;
    const int wave = tid >> 6, lane = tid & 63;
    const int l31 = lane & 31, hi5 = lane >> 5;
    const int bh = blockIdx.y, b = bh >> 4, h = bh & 15;
    const size_t base = (size_t)b * SS * DIM + (size_t)h * HD;
    const int qs0 = blockIdx.x * 128 + wave * 32;
    const int lane8 = lane * 8;
    const int sl0 = wave * 128 + lane, sl1 = sl0 + 64;

    ushortT* K0 = SMEM;
    ushortT* K1 = SMEM + 8192;
    ushortT* V0 = SMEM + 16384;
    ushortT* V1 = SMEM + 24576;

    // ---- Q fragments (B-op: n = q = l31, k = d = ds*16 + hi5*8 + j) ----
    // scale = 1/8 * log2(e) folded in (exp2 domain)
    const float qscale = 0.125f * 1.4426950408889634f;
    FragU Qh[4], Ql[4];
    {
        const int qrow = qs0 + l31;
#pragma unroll
        for (int ds = 0; ds < 4; ds++) {
            const float* p0 = q + base + (size_t)qrow * DIM + ds * 16 + hi5 * 8;
            float4 a = *(const float4*)(p0);
            float4 c = *(const float4*)(p0 + 4);
            float e[8] = {a.x, a.y, a.z, a.w, c.x, c.y, c.z, c.w};
#pragma unroll
            for (int j = 0; j < 8; j++) {
                float x = e[j] * qscale;
                unsigned short hs = f2bf(x);
                Qh[ds].us[j] = hs;
                Ql[ds].us[j] = f2bf(x - bf2f(hs));
            }
        }
    }

    // O^T accumulators: tile dt covers d = dt*32 + row, col q = l31
    float16v Oacc[2];
#pragma unroll
    for (int dt = 0; dt < 2; dt++)
        Oacc[dt] = (float16v){0.f,0.f,0.f,0.f,0.f,0.f,0.f,0.f,
                              0.f,0.f,0.f,0.f,0.f,0.f,0.f,0.f};

    float m_run = -INFINITY;
    float l_run = 0.f;

    auto stage_K = [&](int t, ushortT* dst) {
        const size_t tb = (size_t)(bh * 32 + t) * 4096;
        gld_lds16(KhG + tb + sl0 * 8, &dst[sl0 * 8]);
        gld_lds16(KhG + tb + sl1 * 8, &dst[sl1 * 8]);
        gld_lds16(KlG + tb + sl0 * 8, &dst[4096 + sl0 * 8]);
        gld_lds16(KlG + tb + sl1 * 8, &dst[4096 + sl1 * 8]);
    };
    auto stage_V = [&](int t, ushortT* dst) {
        const size_t tb = (size_t)(bh * 32 + t) * 4096;
        gld_lds16(VhG + tb + sl0 * 8, &dst[sl0 * 8]);
        gld_lds16(VhG + tb + sl1 * 8, &dst[sl1 * 8]);
        gld_lds16(VlG + tb + sl0 * 8, &dst[4096 + sl0 * 8]);
        gld_lds16(VlG + tb + sl1 * 8, &dst[4096 + sl1 * 8]);
    };

    // QK: S^T tile pair from K buffer Kb; C row = kv_local = (reg&3)+8*(reg>>2)+4*hi5
    // (+kvt*32), col = q = l31
    auto qk = [&](const ushortT* Kb, float16v (&st)[2]) {
        const ushortT* KhS = Kb;
        const ushortT* KlS = Kb + 4096;
#pragma unroll
        for (int t = 0; t < 2; t++)
            st[t] = (float16v){0.f,0.f,0.f,0.f,0.f,0.f,0.f,0.f,
                               0.f,0.f,0.f,0.f,0.f,0.f,0.f,0.f};
#pragma unroll
        for (int ds = 0; ds < 4; ds++) {
            FragU kh0, kl0, kh1, kl1;
            kh0.v = *(const short8v*)&KhS[(ds * 2 + 0) * 512 + lane8];
            kl0.v = *(const short8v*)&KlS[(ds * 2 + 0) * 512 + lane8];
            kh1.v = *(const short8v*)&KhS[(ds * 2 + 1) * 512 + lane8];
            kl1.v = *(const short8v*)&KlS[(ds * 2 + 1) * 512 + lane8];
            st[0] = __builtin_amdgcn_mfma_f32_32x32x16_bf16(kh0.v, Qh[ds].v, st[0], 0, 0, 0);
            st[0] = __builtin_amdgcn_mfma_f32_32x32x16_bf16(kh0.v, Ql[ds].v, st[0], 0, 0, 0);
            st[0] = __builtin_amdgcn_mfma_f32_32x32x16_bf16(kl0.v, Qh[ds].v, st[0], 0, 0, 0);
            st[1] = __builtin_amdgcn_mfma_f32_32x32x16_bf16(kh1.v, Qh[ds].v, st[1], 0, 0, 0);
            st[1] = __builtin_amdgcn_mfma_f32_32x32x16_bf16(kh1.v, Ql[ds].v, st[1], 0, 0, 0);
            st[1] = __builtin_amdgcn_mfma_f32_32x32x16_bf16(kl1.v, Qh[ds].v, st[1], 0, 0, 0);
        }
    };

    // softmax stats + P-pack + PV for tile in st, V from Vb. Round-3 math verbatim.
    auto finish = [&](float16v (&st)[2], const ushortT* Vb) {
        const ushortT* VhS = Vb;
        const ushortT* VlS = Vb + 4096;
        float oscale, inv;
        {
            float g[8];
#pragma unroll
            for (int t = 0; t < 2; t++)
#pragma unroll
                for (int i = 0; i < 4; i++)
                    g[t * 4 + i] = fmaxf(fmaxf(st[t][4 * i], st[t][4 * i + 1]),
                                         fmaxf(st[t][4 * i + 2], st[t][4 * i + 3]));
            float vmax = fmaxf(fmaxf(fmaxf(g[0], g[1]), fmaxf(g[2], g[3])),
                               fmaxf(fmaxf(g[4], g[5]), fmaxf(g[6], g[7])));
            vmax = fmaxf(vmax, __shfl_xor(vmax, 32, 64));
            const float mn = fmaxf(m_run, vmax);
            const float al = __builtin_amdgcn_exp2f(m_run - mn);   // 0 on first iter

            float ssum = 0.f;
#pragma unroll
            for (int t = 0; t < 2; t++)
#pragma unroll
                for (int r = 0; r < 16; r++) {
                    const float p = __builtin_amdgcn_exp2f(st[t][r] - mn);
                    st[t][r] = p;
                    ssum += p;
                }
            ssum += __shfl_xor(ssum, 32, 64);
            const float ln = al * l_run + ssum;
            inv = __builtin_amdgcn_rcpf(ln);
            oscale = al * inv;
            // fold the per-step division into P
#pragma unroll
            for (int t = 0; t < 2; t++)
#pragma unroll
                for (int r = 0; r < 16; r++)
                    st[t][r] *= inv;
            m_run = mn;
            l_run = ln;
        }

#pragma unroll
        for (int dt = 0; dt < 2; dt++)
#pragma unroll
            for (int r = 0; r < 16; r++)
                Oacc[dt][r] *= oscale;

#pragma unroll
        for (int kvs = 0; kvs < 4; kvs++) {
            const int kvt = kvs >> 1;
            const int R = (kvs & 1) * 8;
            // B-frag slice kvs needs P'[kv = kvs*16 + hi5_t*8 + j][q = l31_t]:
            //   lane-low  w0=(R0,R1)@lo w1=(R2,R3)@lo w2=(R0,R1)@hi w3=(R2,R3)@hi
            //   lane-high w0=(R4,R5)@lo w1=(R6,R7)@lo w2=(R4,R5)@hi w3=(R6,R7)@hi
            float p0 = st[kvt][R + 0], p1 = st[kvt][R + 1];
            float p2 = st[kvt][R + 2], p3 = st[kvt][R + 3];
            float p4 = st[kvt][R + 4], p5 = st[kvt][R + 5];
            float p6 = st[kvt][R + 6], p7 = st[kvt][R + 7];
            unsigned X0 = cvt_pk_bf16(p0, p1), X1 = cvt_pk_bf16(p2, p3);
            unsigned Y0 = cvt_pk_bf16(p4, p5), Y1 = cvt_pk_bf16(p6, p7);
            float e0 = p0 - __builtin_bit_cast(float, X0 << 16);
            float e1 = p1 - __builtin_bit_cast(float, X0 & 0xffff0000u);
            float e2 = p2 - __builtin_bit_cast(float, X1 << 16);
            float e3 = p3 - __builtin_bit_cast(float, X1 & 0xffff0000u);
            float e4 = p4 - __builtin_bit_cast(float, Y0 << 16);
            float e5 = p5 - __builtin_bit_cast(float, Y0 & 0xffff0000u);
            float e6 = p6 - __builtin_bit_cast(float, Y1 << 16);
            float e7 = p7 - __builtin_bit_cast(float, Y1 & 0xffff0000u);
            unsigned Z0 = cvt_pk_bf16(e0, e1), Z1 = cvt_pk_bf16(e2, e3);
            unsigned W0 = cvt_pk_bf16(e4, e5), W1 = cvt_pk_bf16(e6, e7);
            permlane32_swap(X0, Y0);
            permlane32_swap(X1, Y1);
            permlane32_swap(Z0, W0);
            permlane32_swap(Z1, W1);
            FragU Phf, Plf;
            Phf.u[0] = X0; Phf.u[1] = X1; Phf.u[2] = Y0; Phf.u[3] = Y1;
            Plf.u[0] = Z0; Plf.u[1] = Z1; Plf.u[2] = W0; Plf.u[3] = W1;

#pragma unroll
            for (int dt = 0; dt < 2; dt++) {
                FragU vh, vl;
                vh.v = *(const short8v*)&VhS[(dt * 4 + kvs) * 512 + lane8];
                vl.v = *(const short8v*)&VlS[(dt * 4 + kvs) * 512 + lane8];
                Oacc[dt] = __builtin_amdgcn_mfma_f32_32x32x16_bf16(vh.v, Phf.v, Oacc[dt], 0, 0, 0);
                Oacc[dt] = __builtin_amdgcn_mfma_f32_32x32x16_bf16(vl.v, Phf.v, Oacc[dt], 0, 0, 0);
                Oacc[dt] = __builtin_amdgcn_mfma_f32_32x32x16_bf16(vh.v, Plf.v, Oacc[dt], 0, 0, 0);
            }
        }
    };

    float16v stA[2], stB[2];

    // ---- prologue: publish K(0), K(1), V(0); compute S(0) ----
    stage_K(0, K0);
    stage_K(1, K1);
    stage_V(0, V0);
    __syncthreads();                 // vmcnt drain + publish K0,K1,V0
    qk(K0, stA);
    __syncthreads();                 // all waves done reading K0 (free for K(2))

    // ---- pipelined main loop: iteration jb works on S(jb)=SC, builds S(jb+1)=SN.
    // stage_K(jb+2 -> Kc): Kc's K(jb) consumed in iter jb-1 (pre-barrier)  [WAR ok]
    // stage_V(jb+1 -> Vn): Vn's V(jb-1) consumed in iter jb-1 (pre-barrier) [WAR ok]
    // both published by this iter's end barrier, consumed next iter        [RAW ok]
    auto iter = [&](int jb, float16v (&SC)[2], float16v (&SN)[2],
                    ushortT* Kc, ushortT* Kn, ushortT* Vc, ushortT* Vn) {
        if (jb <= 29) stage_K(jb + 2, Kc);
        if (jb <= 30) stage_V(jb + 1, Vn);
        if (jb <= 30) qk(Kn, SN);    // MFMA on jb+1 — overlaps finish(jb)'s VALU
        finish(SC, Vc);              // stats+pack (VALU) + PV (MFMA) for jb
        __syncthreads();             // drains vmcnt; publishes K(jb+2), V(jb+1)
    };

    for (int jb = 0; jb < 32; jb += 2) {
        iter(jb,     stA, stB, K0, K1, V0, V1);
        iter(jb + 1, stB, stA, K1, K0, V1, V0);
    }

    // ---- epilogue: transpose O^T per tile via wave-local LDS (reuse SMEM),
    //      split-bf16 coalesced store ----
    float* EP = ((float*)SMEM) + wave * 1056;   // [32 q][33 f32] per wave
    const int qq = lane >> 1, dh = (lane & 1) * 16;
#pragma unroll
    for (int dt = 0; dt < 2; dt++) {
#pragma unroll
        for (int g = 0; g < 4; g++) {
            // regs 4g..4g+3 -> d_local = 8g + 4*hi5 + 0..3, col q = l31
            float4 wv = make_float4(Oacc[dt][4 * g + 0], Oacc[dt][4 * g + 1],
                                    Oacc[dt][4 * g + 2], Oacc[dt][4 * g + 3]);
            *(float4*)&EP[l31 * 33 + g * 8 + hi5 * 4] = wv;
        }
        // wave-local region: lgkmcnt orders write->read, no barrier
        float vals[16];
#pragma unroll
        for (int k4 = 0; k4 < 4; k4++)
            *(float4*)&vals[k4 * 4] = *(const float4*)&EP[qq * 33 + dh + k4 * 4];

        unsigned ho[8], lo8[8];
#pragma unroll
        for (int kk = 0; kk < 8; kk++) {
            unsigned short h0, l0, h1, l1;
            split_tr(vals[2 * kk], h0, l0);
            split_tr(vals[2 * kk + 1], h1, l1);
            ho[kk]  = (unsigned)h0 | ((unsigned)h1 << 16);
            lo8[kk] = (unsigned)l0 | ((unsigned)l1 << 16);
        }
        const int qrow = qs0 + qq;
        const size_t off = (size_t)(b * SS + qrow) * DIM + h * HD + dt * 32 + dh;
        *(uint4*)&Oh[off]     = make_uint4(ho[0], ho[1], ho[2], ho[3]);
        *(uint4*)&Oh[off + 8] = make_uint4(ho[4], ho[5], ho[6], ho[7]);
        *(uint4*)&Ol[off]     = make_uint4(lo8[0], lo8[1], lo8[2], lo8[3]);
        *(uint4*)&Ol[off + 8] = make_uint4(lo8[4], lo8[5], lo8[6], lo8[7]);
    }
}

// ---------------------------------------------------------------------------
extern "C" void kernel_launch(void* const* d_in, const int* in_sizes, int n_in,
                              void* d_out, int out_size, void* d_ws, size_t ws_size,
                              hipStream_t stream)
{
    const float* x  = (const float*)d_in[0];
    const float* Wq = (const float*)d_in[1];
    const float* Wk = (const float*)d_in[2];
    const float* Wv = (const float*)d_in[3];
    const float* Wo = (const float*)d_in[4];
    float* out = (float*)d_out;

    char* w = (char*)d_ws;
    float*   qw  = (float*)(w);                        // 16 MB
    float*   kw  = (float*)(w + ((size_t)16 << 20));   // 16 MB (later Oh/Ol)
    ushortT* VhG = (ushortT*)(w + ((size_t)32 << 20)); // 8 MB (V frag tiles, from GEMM)
    ushortT* VlG = (ushortT*)(w + ((size_t)40 << 20)); // 8 MB
    ushortT* XhS = (ushortT*)(w + ((size_t)48 << 20)); // 8 MB
    ushortT* XlS = (ushortT*)(w + ((size_t)56 << 20)); // 8 MB
    ushortT* WtH = (ushortT*)(w + ((size_t)64 << 20)); // 8 MB (4 matrices)
    ushortT* WtL = (ushortT*)(w + ((size_t)72 << 20)); // 8 MB
    ushortT* KhG = (ushortT*)(w + ((size_t)80 << 20)); // 8 MB
    ushortT* KlG = (ushortT*)(w + ((size_t)88 << 20)); // 8 MB  -> 96 MB total
    ushortT* OhS = (ushortT*)kw;                       // reuse after kv_convert
    ushortT* OlS = (ushortT*)(w + ((size_t)24 << 20));

    dim3 blk(256);
    const int n4 = MTOT * DIM / 4;

    // split X -> bf16 hi/lo; transpose+split all four W
    convert_split_kernel<<<dim3(n4 / 256), blk, 0, stream>>>(x, XhS, XlS, n4);
    transpose_split_kernel<<<dim3(16, 16, 4), blk, 0, stream>>>(Wq, Wk, Wv, Wo, WtH, WtL);

    // Q/K/V projections; z==2 (V) emits frag-major split tiles directly
    gemm_bt_split_kernel<<<dim3(8, 32, 3), blk, 0, stream>>>(
        XhS, XlS, WtH, WtL, qw, kw, VhG, VlG);

    // K -> frag-major split tiles (32x32x16 A-op layout)
    kv_convert_kernel<<<dim3(32, 32), blk, 0, stream>>>(kw, KhG, KlG);

    // attention (exact reference recurrence, kv block = 64)
    attn_mfma_kernel<<<dim3(16, 32), blk, 0, stream>>>(qw, KhG, KlG, VhG, VlG, OhS, OlS);

    // output projection (z=0 path, fp32 out)
    gemm_bt_split_kernel<<<dim3(8, 32, 1), blk, 0, stream>>>(
        OhS, OlS, WtH + (size_t)3 * 1024 * 1024, WtL + (size_t)3 * 1024 * 1024,
        out, nullptr, nullptr, nullptr);
}

// Round 8
// 290.793 us; speedup vs baseline: 1.1573x; 1.0717x over previous
//
#include <hip/hip_runtime.h>
#include <hip/hip_bf16.h>
#include <math.h>

#define BB   2
#define SS   2048
#define DIM  1024
#define NH   16
#define HD   64
#define MTOT (BB * SS)   // 4096

typedef unsigned short ushortT;
typedef __attribute__((ext_vector_type(8))) short short8v;   // 8 bf16 (4 VGPRs)
typedef __attribute__((ext_vector_type(4))) float float4v;   // 4 fp32 acc
typedef __attribute__((ext_vector_type(16))) float float16v; // 16 fp32 acc (32x32 MFMA)

union FragU { short8v v; unsigned short us[8]; unsigned int u[4]; };

__device__ inline unsigned short f2bf(float x) {             // fp32 -> bf16 RNE
    unsigned u = __builtin_bit_cast(unsigned, x);
    u += 0x7fffu + ((u >> 16) & 1u);
    return (unsigned short)(u >> 16);
}
__device__ inline float bf2f(unsigned short h) {
    unsigned u = ((unsigned)h) << 16;
    return __builtin_bit_cast(float, u);
}
// truncation split: hi = trunc-to-bf16(x), lo = trunc-to-bf16(x - hi)
__device__ inline void split_tr(float x, unsigned short& hi, unsigned short& lo) {
    unsigned u = __builtin_bit_cast(unsigned, x);
    hi = (unsigned short)(u >> 16);
    float hf = __builtin_bit_cast(float, u & 0xffff0000u);
    lo = (unsigned short)(__builtin_bit_cast(unsigned, x - hf) >> 16);
}
__device__ inline void split4(const float4& x, short4& hi, short4& lo) {
    unsigned short h0 = f2bf(x.x), h1 = f2bf(x.y), h2 = f2bf(x.z), h3 = f2bf(x.w);
    hi = make_short4((short)h0, (short)h1, (short)h2, (short)h3);
    lo = make_short4((short)f2bf(x.x - bf2f(h0)), (short)f2bf(x.y - bf2f(h1)),
                     (short)f2bf(x.z - bf2f(h2)), (short)f2bf(x.w - bf2f(h3)));
}
// async global->LDS, 16 B per lane (dest = wave-uniform base + lane*16)
__device__ inline void gld_lds16(const void* g, void* l) {
    __builtin_amdgcn_global_load_lds(
        (const __attribute__((address_space(1))) void*)g,
        (__attribute__((address_space(3))) void*)l, 16, 0, 0);
}
// packed RNE bf16 convert: lo16 = bf16(a), hi16 = bf16(b)
__device__ inline unsigned cvt_pk_bf16(float a, float b) {
    unsigned r;
    asm("v_cvt_pk_bf16_f32 %0, %1, %2" : "=v"(r) : "v"(a), "v"(b));
    return r;
}
// v_permlane32_swap_b32: a' = [a(0:31), b(0:31)], b' = [a(32:63), b(32:63)]
__device__ inline void permlane32_swap(unsigned &a, unsigned &b) {
    asm("v_permlane32_swap_b32 %0, %1" : "+v"(a), "+v"(b));
}

// ---------------------------------------------------------------------------
// fp32 -> bf16 hi/lo elementwise split (X)
// ---------------------------------------------------------------------------
__global__ __launch_bounds__(256) void convert_split_kernel(
    const float* __restrict__ in, ushortT* __restrict__ hi, ushortT* __restrict__ lo, int n4)
{
    int t = blockIdx.x * 256 + threadIdx.x;
    if (t < n4) {
        float4 x = ((const float4*)in)[t];
        short4 h, l; split4(x, h, l);
        ((short4*)hi)[t] = h;
        ((short4*)lo)[t] = l;
    }
}

// ---------------------------------------------------------------------------
// W (1024x1024 fp32, K-major) -> W^T (bf16 hi/lo, N-major rows of K)
// ---------------------------------------------------------------------------
__global__ __launch_bounds__(256) void transpose_split_kernel(
    const float* __restrict__ W0, const float* __restrict__ W1,
    const float* __restrict__ W2, const float* __restrict__ W3,
    ushortT* __restrict__ WtH, ushortT* __restrict__ WtL)
{
    const int z = blockIdx.z;
    const float* __restrict__ W = (z == 0) ? W0 : (z == 1) ? W1 : (z == 2) ? W2 : W3;
    ushortT* H = WtH + (size_t)z * 1024 * 1024;
    ushortT* L = WtL + (size_t)z * 1024 * 1024;

    __shared__ float T[64][65];
    const int k0 = blockIdx.y * 64, n0 = blockIdx.x * 64;
    const int tid = threadIdx.x;
    const int c4 = (tid & 15) * 4;

#pragma unroll
    for (int i = 0; i < 4; i++) {
        int r = (tid >> 4) + 16 * i;
        *(float4*)&T[r][c4] = *(const float4*)(W + (size_t)(k0 + r) * 1024 + n0 + c4);
    }
    __syncthreads();
#pragma unroll
    for (int i = 0; i < 4; i++) {
        int n = (tid >> 4) + 16 * i;
        float4 vv = make_float4(T[c4 + 0][n], T[c4 + 1][n], T[c4 + 2][n], T[c4 + 3][n]);
        short4 h, l; split4(vv, h, l);
        *(short4*)&H[(size_t)(n0 + n) * 1024 + k0 + c4] = h;
        *(short4*)&L[(size_t)(n0 + n) * 1024 + k0 + c4] = l;
    }
}

// ---------------------------------------------------------------------------
// K fp32 (B,S,H*D) -> bf16 hi/lo 64x64 tiles, frag-major for 32x32x16 A-op.
// Frag f = ds*2 + kvt: element (kv = kvt*32 + (lane&31), d = ds*16 + (lane>>5)*8 + j)
// ---------------------------------------------------------------------------
__global__ __launch_bounds__(256) void kv_convert_kernel(
    const float* __restrict__ kw,
    ushortT* __restrict__ KhG, ushortT* __restrict__ KlG)
{
    const int jb = blockIdx.x, bh = blockIdx.y;
    const int b = bh >> 4, h = bh & 15;

    __shared__ float T[64][68];
    const int tid = threadIdx.x;
    const size_t ibase = (size_t)b * SS * DIM + (size_t)h * HD + (size_t)(jb * 64) * DIM;
    const int c4 = (tid & 15) * 4;
#pragma unroll
    for (int i = 0; i < 4; i++) {
        int r = (tid >> 4) + 16 * i;
        *(float4*)&T[r][c4] = *(const float4*)(kw + ibase + (size_t)r * DIM + c4);
    }
    __syncthreads();

    ushortT* oh = KhG + (size_t)(bh * 32 + jb) * 4096;
    ushortT* ol = KlG + (size_t)(bh * 32 + jb) * 4096;

#pragma unroll
    for (int i = 0; i < 2; i++) {
        const int s = tid + i * 256;          // slot 0..511
        const int f = s >> 6;                 // frag 0..7
        const int lane = s & 63;
        const int ds = f >> 1, kvt = f & 1;
        const int kv = kvt * 32 + (lane & 31);
        const int d0 = ds * 16 + (lane >> 5) * 8;
        ushortT hv[8], lv[8];
#pragma unroll
        for (int j = 0; j < 8; j++) split_tr(T[kv][d0 + j], hv[j], lv[j]);
        *(short4*)&oh[s * 8]     = *(short4*)&hv[0];
        *(short4*)&oh[s * 8 + 4] = *(short4*)&hv[4];
        *(short4*)&ol[s * 8]     = *(short4*)&lv[0];
        *(short4*)&ol[s * 8 + 4] = *(short4*)&lv[4];
    }
}

// ---------------------------------------------------------------------------
// Split-bf16 MFMA GEMM. z==2 (V projection) stores its output DIRECTLY as
// split-bf16 frag-major 32x32x16 V^T A-op tiles. z==0/1 store fp32 rows.
// BK=64 + both-sides XOR swizzle (round-7, verified: +8 µs pool gain).
// Round-8: XCD-chunked bijective block remap (T1/m192 form): each XCD owns a
// contiguous 4-m-panel chunk (A 2MB L2-resident, B 4MB cycles) instead of
// every-8th block (A fetched 8x across XCDs).
// launch_bounds (256,2): 2 blocks/CU (VGPR-capped; (256,3) cost ~18 µs).
// Round-6 lesson: K-projection fusion here was net-negative; kv_convert kept.
// ---------------------------------------------------------------------------
__global__ __launch_bounds__(256, 2) void gemm_bt_split_kernel(
    const ushortT* __restrict__ Ah, const ushortT* __restrict__ Al,
    const ushortT* __restrict__ BtH, const ushortT* __restrict__ BtL,
    float* __restrict__ Y0, float* __restrict__ Y1,
    ushortT* __restrict__ VhG, ushortT* __restrict__ VlG)
{
    const int z = blockIdx.z;
    const ushortT* __restrict__ Bh = BtH + (size_t)z * 1024 * 1024;
    const ushortT* __restrict__ Bl = BtL + (size_t)z * 1024 * 1024;

    const int K = 1024, N = 1024;
    // XCD-chunked remap (bijective, grid 8x32 per z; 256%8==0):
    // wid%8 selects XCD (round-robin dispatch); XCD x processes contiguous
    // work ids [32x, 32x+32) = m-panels by in [4x, 4x+4).
    const int wid  = blockIdx.x + (blockIdx.y << 3);
    const int work = ((wid & 7) << 5) + (wid >> 3);
    const int m0 = (work >> 3) * 128;
    const int n0 = (work & 7) * 128;

    __shared__ __align__(16) ushortT AhS[128 * 64];
    __shared__ __align__(16) ushortT AlS[128 * 64];
    __shared__ __align__(16) ushortT BhS[128 * 64];
    __shared__ __align__(16) ushortT BlS[128 * 64];

    const int tid  = threadIdx.x;
    const int wave = tid >> 6, lane = tid & 63;
    const int quad = lane >> 4, l15 = lane & 15;
    const int wm = wave >> 1, wn = wave & 1;
    const int rx = l15 & 7;                 // read-side swizzle key

    float4v acc[4][4];
#pragma unroll
    for (int i = 0; i < 4; i++)
#pragma unroll
        for (int j = 0; j < 4; j++) acc[i][j] = (float4v){0.f, 0.f, 0.f, 0.f};

    for (int k0 = 0; k0 < K; k0 += 64) {
        __syncthreads();
#pragma unroll
        for (int i = 0; i < 4; i++) {
            const int s = tid + i * 256;    // slot 0..1023: row r = s>>3, blk = s&7
            const int r = s >> 3;
            // swizzle: LDS 16B-block (r, s&7) holds global k-block ((s&7) ^ (r&7))
            const int kk = ((s & 7) ^ (r & 7)) * 8;
            gld_lds16(Ah + (size_t)(m0 + r) * K + k0 + kk, &AhS[s * 8]);
            gld_lds16(Al + (size_t)(m0 + r) * K + k0 + kk, &AlS[s * 8]);
            gld_lds16(Bh + (size_t)(n0 + r) * K + k0 + kk, &BhS[s * 8]);
            gld_lds16(Bl + (size_t)(n0 + r) * K + k0 + kk, &BlS[s * 8]);
        }
        __syncthreads();

#pragma unroll
        for (int ks = 0; ks < 2; ks++) {
            FragU ah[4], al[4], bh[4], bl[4];
#pragma unroll
            for (int t = 0; t < 4; t++) {
                const int ra = wm * 64 + t * 16 + l15;   // ra&7 == rx
                const int rb = wn * 64 + t * 16 + l15;
                const int boff = ((ks * 4 + quad) ^ rx) * 8;
                ah[t].v = *(const short8v*)&AhS[ra * 64 + boff];
                al[t].v = *(const short8v*)&AlS[ra * 64 + boff];
                bh[t].v = *(const short8v*)&BhS[rb * 64 + boff];
                bl[t].v = *(const short8v*)&BlS[rb * 64 + boff];
            }
#pragma unroll
            for (int mt = 0; mt < 4; mt++)
#pragma unroll
                for (int nt = 0; nt < 4; nt++) {
                    acc[mt][nt] = __builtin_amdgcn_mfma_f32_16x16x32_bf16(ah[mt].v, bh[nt].v, acc[mt][nt], 0, 0, 0);
                    acc[mt][nt] = __builtin_amdgcn_mfma_f32_16x16x32_bf16(ah[mt].v, bl[nt].v, acc[mt][nt], 0, 0, 0);
                    acc[mt][nt] = __builtin_amdgcn_mfma_f32_16x16x32_bf16(al[mt].v, bh[nt].v, acc[mt][nt], 0, 0, 0);
                }
        }
    }

    if (z == 2) {
        // ---- V epilogue: direct frag-major split-bf16 V^T A-op tile store ----
        // acc element: (kv_local = mt*16 + quad*4 + r, d_local = nt*16 + l15)
        // target frag f = (nt>>1)*4 + mt, lane_t = (quad>>1)*32 + (nt&1)*16 + l15,
        // j = (quad&1)*4 + r  -> r-consecutive
        const int b  = m0 >> 11;
        const int jb = ((m0 & 2047) >> 6) + wm;
        const int h  = (n0 >> 6) + wn;
        const size_t tb = (size_t)((b * 16 + h) * 32 + jb) * 4096;
        ushortT* vh = VhG + tb;
        ushortT* vl = VlG + tb;
#pragma unroll
        for (int mt = 0; mt < 4; mt++)
#pragma unroll
            for (int nt = 0; nt < 4; nt++) {
                const int off = ((((nt >> 1) * 4 + mt) * 64 +
                                  (quad >> 1) * 32 + (nt & 1) * 16 + l15) * 8) +
                                (quad & 1) * 4;
                float4 vv = make_float4(acc[mt][nt][0], acc[mt][nt][1],
                                        acc[mt][nt][2], acc[mt][nt][3]);
                unsigned short h0, l0, h1, l1, h2, l2, h3, l3;
                split_tr(vv.x, h0, l0); split_tr(vv.y, h1, l1);
                split_tr(vv.z, h2, l2); split_tr(vv.w, h3, l3);
                *(short4*)&vh[off] = make_short4((short)h0, (short)h1, (short)h2, (short)h3);
                *(short4*)&vl[off] = make_short4((short)l0, (short)l1, (short)l2, (short)l3);
            }
    } else {
        float* __restrict__ Y = (z == 0) ? Y0 : Y1;
#pragma unroll
        for (int mt = 0; mt < 4; mt++)
#pragma unroll
            for (int r = 0; r < 4; r++) {
                const int row = m0 + wm * 64 + mt * 16 + quad * 4 + r;
                float* yp = Y + (size_t)row * N + n0 + wn * 64 + l15;
#pragma unroll
                for (int nt = 0; nt < 4; nt++)
                    yp[nt * 16] = acc[mt][nt][r];
            }
    }
}

// ---------------------------------------------------------------------------
// MFMA attention, 32x32x16. Round-8 changes on the round-4 pipeline:
//  * XCD-chunked block remap: 4 heads per XCD -> K/V (4MB) L2-resident
//    instead of every head's K/V fetched by all 8 XCDs (FETCH 139MB vs 48
//    unique). Bijective (512 = 8 XCD x 64).
//  * W-form accumulator (EXACT, not round-2's telescoping error): keep
//    W_t = l_t * o_t. W_t = (al_t*inv_{t-1})*W_{t-1} + P_t V_t; O = W*inv_last.
//    Induction: W_t*inv_t == o_t^ref. Removes the per-iter P*=inv (32 muls);
//    P stays in (0,1] so split precision unchanged.
// Pipeline: QK(jb+1) before finish(jb); K 2-ahead, V 1-ahead; 1 barrier/iter.
// NO setprio (round-5: cost 2.9 µs, m190-consistent).
// ---------------------------------------------------------------------------
__global__ __launch_bounds__(256, 2) void attn_mfma_kernel(
    const float* __restrict__ q,
    const ushortT* __restrict__ KhG, const ushortT* __restrict__ KlG,
    const ushortT* __restrict__ VhG, const ushortT* __restrict__ VlG,
    ushortT* __restrict__ Oh, ushortT* __restrict__ Ol)
{
    // layout (ushort units): K0 @0, K1 @8192, V0 @16384, V1 @24576
    // each Kx/Vx = {hi 4096, lo 4096}
    __shared__ __align__(16) ushortT SMEM[32768];   // 64 KiB

    const int tid  = threadIdx.x;
    const int wave = tid >> 6, lane = tid & 63;
    const int l31 = lane & 31, hi5 = lane >> 5;
    // XCD-chunked remap: wid%8 = XCD (round-robin dispatch); XCD x owns work
    // ids [64x, 64x+64) = heads bh in [4x, 4x+4) (K/V 4MB -> one L2).
    const int wid  = blockIdx.x + (blockIdx.y << 4);
    const int work = ((wid & 7) << 6) + (wid >> 3);
    const int qx = work & 15;
    const int bh = work >> 4;
    const int b = bh >> 4, h = bh & 15;
    const size_t base = (size_t)b * SS * DIM + (size_t)h * HD;
    const int qs0 = qx * 128 + wave * 32;
    const int lane8 = lane * 8;
    const int sl0 = wave * 128 + lane, sl1 = sl0 + 64;

    ushortT* K0 = SMEM;
    ushortT* K1 = SMEM + 8192;
    ushortT* V0 = SMEM + 16384;
    ushortT* V1 = SMEM + 24576;

    // ---- Q fragments (B-op: n = q = l31, k = d = ds*16 + hi5*8 + j) ----
    // scale = 1/8 * log2(e) folded in (exp2 domain)
    const float qscale = 0.125f * 1.4426950408889634f;
    FragU Qh[4], Ql[4];
    {
        const int qrow = qs0 + l31;
#pragma unroll
        for (int ds = 0; ds < 4; ds++) {
            const float* p0 = q + base + (size_t)qrow * DIM + ds * 16 + hi5 * 8;
            float4 a = *(const float4*)(p0);
            float4 c = *(const float4*)(p0 + 4);
            float e[8] = {a.x, a.y, a.z, a.w, c.x, c.y, c.z, c.w};
#pragma unroll
            for (int j = 0; j < 8; j++) {
                float x = e[j] * qscale;
                unsigned short hs = f2bf(x);
                Qh[ds].us[j] = hs;
                Ql[ds].us[j] = f2bf(x - bf2f(hs));
            }
        }
    }

    // W accumulators (= l_run * O): tile dt covers d = dt*32 + row, col q = l31
    float16v Oacc[2];
#pragma unroll
    for (int dt = 0; dt < 2; dt++)
        Oacc[dt] = (float16v){0.f,0.f,0.f,0.f,0.f,0.f,0.f,0.f,
                              0.f,0.f,0.f,0.f,0.f,0.f,0.f,0.f};

    float m_run = -INFINITY;
    float l_run = 0.f;
    float inv_prev = 1.0f;   // 1/l_{t-1}; arbitrary at t=0 (al=0 kills it)

    auto stage_K = [&](int t, ushortT* dst) {
        const size_t tb = (size_t)(bh * 32 + t) * 4096;
        gld_lds16(KhG + tb + sl0 * 8, &dst[sl0 * 8]);
        gld_lds16(KhG + tb + sl1 * 8, &dst[sl1 * 8]);
        gld_lds16(KlG + tb + sl0 * 8, &dst[4096 + sl0 * 8]);
        gld_lds16(KlG + tb + sl1 * 8, &dst[4096 + sl1 * 8]);
    };
    auto stage_V = [&](int t, ushortT* dst) {
        const size_t tb = (size_t)(bh * 32 + t) * 4096;
        gld_lds16(VhG + tb + sl0 * 8, &dst[sl0 * 8]);
        gld_lds16(VhG + tb + sl1 * 8, &dst[sl1 * 8]);
        gld_lds16(VlG + tb + sl0 * 8, &dst[4096 + sl0 * 8]);
        gld_lds16(VlG + tb + sl1 * 8, &dst[4096 + sl1 * 8]);
    };

    // QK: S^T tile pair from K buffer Kb; C row = kv_local = (reg&3)+8*(reg>>2)+4*hi5
    // (+kvt*32), col = q = l31
    auto qk = [&](const ushortT* Kb, float16v (&st)[2]) {
        const ushortT* KhS = Kb;
        const ushortT* KlS = Kb + 4096;
#pragma unroll
        for (int t = 0; t < 2; t++)
            st[t] = (float16v){0.f,0.f,0.f,0.f,0.f,0.f,0.f,0.f,
                               0.f,0.f,0.f,0.f,0.f,0.f,0.f,0.f};
#pragma unroll
        for (int ds = 0; ds < 4; ds++) {
            FragU kh0, kl0, kh1, kl1;
            kh0.v = *(const short8v*)&KhS[(ds * 2 + 0) * 512 + lane8];
            kl0.v = *(const short8v*)&KlS[(ds * 2 + 0) * 512 + lane8];
            kh1.v = *(const short8v*)&KhS[(ds * 2 + 1) * 512 + lane8];
            kl1.v = *(const short8v*)&KlS[(ds * 2 + 1) * 512 + lane8];
            st[0] = __builtin_amdgcn_mfma_f32_32x32x16_bf16(kh0.v, Qh[ds].v, st[0], 0, 0, 0);
            st[0] = __builtin_amdgcn_mfma_f32_32x32x16_bf16(kh0.v, Ql[ds].v, st[0], 0, 0, 0);
            st[0] = __builtin_amdgcn_mfma_f32_32x32x16_bf16(kl0.v, Qh[ds].v, st[0], 0, 0, 0);
            st[1] = __builtin_amdgcn_mfma_f32_32x32x16_bf16(kh1.v, Qh[ds].v, st[1], 0, 0, 0);
            st[1] = __builtin_amdgcn_mfma_f32_32x32x16_bf16(kh1.v, Ql[ds].v, st[1], 0, 0, 0);
            st[1] = __builtin_amdgcn_mfma_f32_32x32x16_bf16(kl1.v, Qh[ds].v, st[1], 0, 0, 0);
        }
    };

    // softmax stats + P-pack + PV for tile in st, V from Vb. W-form scalars.
    auto finish = [&](float16v (&st)[2], const ushortT* Vb) {
        const ushortT* VhS = Vb;
        const ushortT* VlS = Vb + 4096;
        float wscale;
        {
            float g[8];
#pragma unroll
            for (int t = 0; t < 2; t++)
#pragma unroll
                for (int i = 0; i < 4; i++)
                    g[t * 4 + i] = fmaxf(fmaxf(st[t][4 * i], st[t][4 * i + 1]),
                                         fmaxf(st[t][4 * i + 2], st[t][4 * i + 3]));
            float vmax = fmaxf(fmaxf(fmaxf(g[0], g[1]), fmaxf(g[2], g[3])),
                               fmaxf(fmaxf(g[4], g[5]), fmaxf(g[6], g[7])));
            vmax = fmaxf(vmax, __shfl_xor(vmax, 32, 64));
            const float mn = fmaxf(m_run, vmax);
            const float al = __builtin_amdgcn_exp2f(m_run - mn);   // 0 on first iter

            float ssum = 0.f;
#pragma unroll
            for (int t = 0; t < 2; t++)
#pragma unroll
                for (int r = 0; r < 16; r++) {
                    const float p = __builtin_amdgcn_exp2f(st[t][r] - mn);
                    st[t][r] = p;
                    ssum += p;
                }
            ssum += __shfl_xor(ssum, 32, 64);
            const float ln = al * l_run + ssum;
            wscale = al * inv_prev;          // al / l_{t-1}: carries prev division
            inv_prev = __builtin_amdgcn_rcpf(ln);
            m_run = mn;
            l_run = ln;
        }

#pragma unroll
        for (int dt = 0; dt < 2; dt++)
#pragma unroll
            for (int r = 0; r < 16; r++)
                Oacc[dt][r] *= wscale;

#pragma unroll
        for (int kvs = 0; kvs < 4; kvs++) {
            const int kvt = kvs >> 1;
            const int R = (kvs & 1) * 8;
            // B-frag slice kvs needs P^T[kv = kvs*16 + hi5_t*8 + j][q = l31_t]:
            //   lane-low  w0=(R0,R1)@lo w1=(R2,R3)@lo w2=(R0,R1)@hi w3=(R2,R3)@hi
            //   lane-high w0=(R4,R5)@lo w1=(R6,R7)@lo w2=(R4,R5)@hi w3=(R6,R7)@hi
            float p0 = st[kvt][R + 0], p1 = st[kvt][R + 1];
            float p2 = st[kvt][R + 2], p3 = st[kvt][R + 3];
            float p4 = st[kvt][R + 4], p5 = st[kvt][R + 5];
            float p6 = st[kvt][R + 6], p7 = st[kvt][R + 7];
            unsigned X0 = cvt_pk_bf16(p0, p1), X1 = cvt_pk_bf16(p2, p3);
            unsigned Y0 = cvt_pk_bf16(p4, p5), Y1 = cvt_pk_bf16(p6, p7);
            float e0 = p0 - __builtin_bit_cast(float, X0 << 16);
            float e1 = p1 - __builtin_bit_cast(float, X0 & 0xffff0000u);
            float e2 = p2 - __builtin_bit_cast(float, X1 << 16);
            float e3 = p3 - __builtin_bit_cast(float, X1 & 0xffff0000u);
            float e4 = p4 - __builtin_bit_cast(float, Y0 << 16);
            float e5 = p5 - __builtin_bit_cast(float, Y0 & 0xffff0000u);
            float e6 = p6 - __builtin_bit_cast(float, Y1 << 16);
            float e7 = p7 - __builtin_bit_cast(float, Y1 & 0xffff0000u);
            unsigned Z0 = cvt_pk_bf16(e0, e1), Z1 = cvt_pk_bf16(e2, e3);
            unsigned W0 = cvt_pk_bf16(e4, e5), W1 = cvt_pk_bf16(e6, e7);
            permlane32_swap(X0, Y0);
            permlane32_swap(X1, Y1);
            permlane32_swap(Z0, W0);
            permlane32_swap(Z1, W1);
            FragU Phf, Plf;
            Phf.u[0] = X0; Phf.u[1] = X1; Phf.u[2] = Y0; Phf.u[3] = Y1;
            Plf.u[0] = Z0; Plf.u[1] = Z1; Plf.u[2] = W0; Plf.u[3] = W1;

#pragma unroll
            for (int dt = 0; dt < 2; dt++) {
                FragU vh, vl;
                vh.v = *(const short8v*)&VhS[(dt * 4 + kvs) * 512 + lane8];
                vl.v = *(const short8v*)&VlS[(dt * 4 + kvs) * 512 + lane8];
                Oacc[dt] = __builtin_amdgcn_mfma_f32_32x32x16_bf16(vh.v, Phf.v, Oacc[dt], 0, 0, 0);
                Oacc[dt] = __builtin_amdgcn_mfma_f32_32x32x16_bf16(vl.v, Phf.v, Oacc[dt], 0, 0, 0);
                Oacc[dt] = __builtin_amdgcn_mfma_f32_32x32x16_bf16(vh.v, Plf.v, Oacc[dt], 0, 0, 0);
            }
        }
    };

    float16v stA[2], stB[2];

    // ---- prologue: publish K(0), K(1), V(0); compute S(0) ----
    stage_K(0, K0);
    stage_K(1, K1);
    stage_V(0, V0);
    __syncthreads();                 // vmcnt drain + publish K0,K1,V0
    qk(K0, stA);
    __syncthreads();                 // all waves done reading K0 (free for K(2))

    // ---- pipelined main loop: iteration jb works on S(jb)=SC, builds S(jb+1)=SN.
    // stage_K(jb+2 -> Kc): Kc's K(jb) consumed in iter jb-1 (pre-barrier)  [WAR ok]
    // stage_V(jb+1 -> Vn): Vn's V(jb-1) consumed in iter jb-1 (pre-barrier) [WAR ok]
    // both published by this iter's end barrier, consumed next iter        [RAW ok]
    auto iter = [&](int jb, float16v (&SC)[2], float16v (&SN)[2],
                    ushortT* Kc, ushortT* Kn, ushortT* Vc, ushortT* Vn) {
        if (jb <= 29) stage_K(jb + 2, Kc);
        if (jb <= 30) stage_V(jb + 1, Vn);
        if (jb <= 30) qk(Kn, SN);    // MFMA on jb+1 — overlaps finish(jb)'s VALU
        finish(SC, Vc);              // stats+pack (VALU) + PV (MFMA) for jb
        __syncthreads();             // drains vmcnt; publishes K(jb+2), V(jb+1)
    };

    for (int jb = 0; jb < 32; jb += 2) {
        iter(jb,     stA, stB, K0, K1, V0, V1);
        iter(jb + 1, stB, stA, K1, K0, V1, V0);
    }

    // ---- deferred final division: O = W * (1/l_last) ----
#pragma unroll
    for (int dt = 0; dt < 2; dt++)
#pragma unroll
        for (int r = 0; r < 16; r++)
            Oacc[dt][r] *= inv_prev;

    // ---- epilogue: transpose O^T per tile via wave-local LDS (reuse SMEM),
    //      split-bf16 coalesced store ----
    float* EP = ((float*)SMEM) + wave * 1056;   // [32 q][33 f32] per wave
    const int qq = lane >> 1, dh = (lane & 1) * 16;
#pragma unroll
    for (int dt = 0; dt < 2; dt++) {
#pragma unroll
        for (int g = 0; g < 4; g++) {
            // regs 4g..4g+3 -> d_local = 8g + 4*hi5 + 0..3, col q = l31
            float4 wv = make_float4(Oacc[dt][4 * g + 0], Oacc[dt][4 * g + 1],
                                    Oacc[dt][4 * g + 2], Oacc[dt][4 * g + 3]);
            *(float4*)&EP[l31 * 33 + g * 8 + hi5 * 4] = wv;
        }
        // wave-local region: lgkmcnt orders write->read, no barrier
        float vals[16];
#pragma unroll
        for (int k4 = 0; k4 < 4; k4++)
            *(float4*)&vals[k4 * 4] = *(const float4*)&EP[qq * 33 + dh + k4 * 4];

        unsigned ho[8], lo8[8];
#pragma unroll
        for (int kk = 0; kk < 8; kk++) {
            unsigned short h0, l0, h1, l1;
            split_tr(vals[2 * kk], h0, l0);
            split_tr(vals[2 * kk + 1], h1, l1);
            ho[kk]  = (unsigned)h0 | ((unsigned)h1 << 16);
            lo8[kk] = (unsigned)l0 | ((unsigned)l1 << 16);
        }
        const int qrow = qs0 + qq;
        const size_t off = (size_t)(b * SS + qrow) * DIM + h * HD + dt * 32 + dh;
        *(uint4*)&Oh[off]     = make_uint4(ho[0], ho[1], ho[2], ho[3]);
        *(uint4*)&Oh[off + 8] = make_uint4(ho[4], ho[5], ho[6], ho[7]);
        *(uint4*)&Ol[off]     = make_uint4(lo8[0], lo8[1], lo8[2], lo8[3]);
        *(uint4*)&Ol[off + 8] = make_uint4(lo8[4], lo8[5], lo8[6], lo8[7]);
    }
}

// ---------------------------------------------------------------------------
extern "C" void kernel_launch(void* const* d_in, const int* in_sizes, int n_in,
                              void* d_out, int out_size, void* d_ws, size_t ws_size,
                              hipStream_t stream)
{
    const float* x  = (const float*)d_in[0];
    const float* Wq = (const float*)d_in[1];
    const float* Wk = (const float*)d_in[2];
    const float* Wv = (const float*)d_in[3];
    const float* Wo = (const float*)d_in[4];
    float* out = (float*)d_out;

    char* w = (char*)d_ws;
    float*   qw  = (float*)(w);                        // 16 MB
    float*   kw  = (float*)(w + ((size_t)16 << 20));   // 16 MB (later Oh/Ol)
    ushortT* VhG = (ushortT*)(w + ((size_t)32 << 20)); // 8 MB (V frag tiles, from GEMM)
    ushortT* VlG = (ushortT*)(w + ((size_t)40 << 20)); // 8 MB
    ushortT* XhS = (ushortT*)(w + ((size_t)48 << 20)); // 8 MB
    ushortT* XlS = (ushortT*)(w + ((size_t)56 << 20)); // 8 MB
    ushortT* WtH = (ushortT*)(w + ((size_t)64 << 20)); // 8 MB (4 matrices)
    ushortT* WtL = (ushortT*)(w + ((size_t)72 << 20)); // 8 MB
    ushortT* KhG = (ushortT*)(w + ((size_t)80 << 20)); // 8 MB
    ushortT* KlG = (ushortT*)(w + ((size_t)88 << 20)); // 8 MB  -> 96 MB total
    ushortT* OhS = (ushortT*)kw;                       // reuse after kv_convert
    ushortT* OlS = (ushortT*)(w + ((size_t)24 << 20));

    dim3 blk(256);
    const int n4 = MTOT * DIM / 4;

    // split X -> bf16 hi/lo; transpose+split all four W
    convert_split_kernel<<<dim3(n4 / 256), blk, 0, stream>>>(x, XhS, XlS, n4);
    transpose_split_kernel<<<dim3(16, 16, 4), blk, 0, stream>>>(Wq, Wk, Wv, Wo, WtH, WtL);

    // Q/K/V projections; z==2 (V) emits frag-major split tiles directly
    gemm_bt_split_kernel<<<dim3(8, 32, 3), blk, 0, stream>>>(
        XhS, XlS, WtH, WtL, qw, kw, VhG, VlG);

    // K -> frag-major split tiles (32x32x16 A-op layout)
    kv_convert_kernel<<<dim3(32, 32), blk, 0, stream>>>(kw, KhG, KlG);

    // attention (exact reference recurrence, kv block = 64)
    attn_mfma_kernel<<<dim3(16, 32), blk, 0, stream>>>(qw, KhG, KlG, VhG, VlG, OhS, OlS);

    // output projection (z=0 path, fp32 out)
    gemm_bt_split_kernel<<<dim3(8, 32, 1), blk, 0, stream>>>(
        OhS, OlS, WtH + (size_t)3 * 1024 * 1024, WtL + (size_t)3 * 1024 * 1024,
        out, nullptr, nullptr, nullptr);
}

// Round 9
// 286.781 us; speedup vs baseline: 1.1735x; 1.0140x over previous
//
#include <hip/hip_runtime.h>
#include <hip/hip_bf16.h>
#include <math.h>

#define BB   2
#define SS   2048
#define DIM  1024
#define NH   16
#define HD   64
#define MTOT (BB * SS)   // 4096

typedef unsigned short ushortT;
typedef __attribute__((ext_vector_type(8))) short short8v;   // 8 bf16 (4 VGPRs)
typedef __attribute__((ext_vector_type(4))) float float4v;   // 4 fp32 acc
typedef __attribute__((ext_vector_type(16))) float float16v; // 16 fp32 acc (32x32 MFMA)

union FragU { short8v v; unsigned short us[8]; unsigned int u[4]; };

__device__ inline unsigned short f2bf(float x) {             // fp32 -> bf16 RNE
    unsigned u = __builtin_bit_cast(unsigned, x);
    u += 0x7fffu + ((u >> 16) & 1u);
    return (unsigned short)(u >> 16);
}
__device__ inline float bf2f(unsigned short h) {
    unsigned u = ((unsigned)h) << 16;
    return __builtin_bit_cast(float, u);
}
// truncation split: hi = trunc-to-bf16(x), lo = trunc-to-bf16(x - hi)
__device__ inline void split_tr(float x, unsigned short& hi, unsigned short& lo) {
    unsigned u = __builtin_bit_cast(unsigned, x);
    hi = (unsigned short)(u >> 16);
    float hf = __builtin_bit_cast(float, u & 0xffff0000u);
    lo = (unsigned short)(__builtin_bit_cast(unsigned, x - hf) >> 16);
}
__device__ inline void split4(const float4& x, short4& hi, short4& lo) {
    unsigned short h0 = f2bf(x.x), h1 = f2bf(x.y), h2 = f2bf(x.z), h3 = f2bf(x.w);
    hi = make_short4((short)h0, (short)h1, (short)h2, (short)h3);
    lo = make_short4((short)f2bf(x.x - bf2f(h0)), (short)f2bf(x.y - bf2f(h1)),
                     (short)f2bf(x.z - bf2f(h2)), (short)f2bf(x.w - bf2f(h3)));
}
// async global->LDS, 16 B per lane (dest = wave-uniform base + lane*16)
__device__ inline void gld_lds16(const void* g, void* l) {
    __builtin_amdgcn_global_load_lds(
        (const __attribute__((address_space(1))) void*)g,
        (__attribute__((address_space(3))) void*)l, 16, 0, 0);
}
// packed RNE bf16 convert: lo16 = bf16(a), hi16 = bf16(b)
__device__ inline unsigned cvt_pk_bf16(float a, float b) {
    unsigned r;
    asm("v_cvt_pk_bf16_f32 %0, %1, %2" : "=v"(r) : "v"(a), "v"(b));
    return r;
}
// v_permlane32_swap_b32: a' = [a(0:31), b(0:31)], b' = [a(32:63), b(32:63)]
__device__ inline void permlane32_swap(unsigned &a, unsigned &b) {
    asm("v_permlane32_swap_b32 %0, %1" : "+v"(a), "+v"(b));
}

// ---------------------------------------------------------------------------
// fp32 -> bf16 hi/lo elementwise split (X)
// ---------------------------------------------------------------------------
__global__ __launch_bounds__(256) void convert_split_kernel(
    const float* __restrict__ in, ushortT* __restrict__ hi, ushortT* __restrict__ lo, int n4)
{
    int t = blockIdx.x * 256 + threadIdx.x;
    if (t < n4) {
        float4 x = ((const float4*)in)[t];
        short4 h, l; split4(x, h, l);
        ((short4*)hi)[t] = h;
        ((short4*)lo)[t] = l;
    }
}

// ---------------------------------------------------------------------------
// W (1024x1024 fp32, K-major) -> W^T (bf16 hi/lo, N-major rows of K)
// ---------------------------------------------------------------------------
__global__ __launch_bounds__(256) void transpose_split_kernel(
    const float* __restrict__ W0, const float* __restrict__ W1,
    const float* __restrict__ W2, const float* __restrict__ W3,
    ushortT* __restrict__ WtH, ushortT* __restrict__ WtL)
{
    const int z = blockIdx.z;
    const float* __restrict__ W = (z == 0) ? W0 : (z == 1) ? W1 : (z == 2) ? W2 : W3;
    ushortT* H = WtH + (size_t)z * 1024 * 1024;
    ushortT* L = WtL + (size_t)z * 1024 * 1024;

    __shared__ float T[64][65];
    const int k0 = blockIdx.y * 64, n0 = blockIdx.x * 64;
    const int tid = threadIdx.x;
    const int c4 = (tid & 15) * 4;

#pragma unroll
    for (int i = 0; i < 4; i++) {
        int r = (tid >> 4) + 16 * i;
        *(float4*)&T[r][c4] = *(const float4*)(W + (size_t)(k0 + r) * 1024 + n0 + c4);
    }
    __syncthreads();
#pragma unroll
    for (int i = 0; i < 4; i++) {
        int n = (tid >> 4) + 16 * i;
        float4 vv = make_float4(T[c4 + 0][n], T[c4 + 1][n], T[c4 + 2][n], T[c4 + 3][n]);
        short4 h, l; split4(vv, h, l);
        *(short4*)&H[(size_t)(n0 + n) * 1024 + k0 + c4] = h;
        *(short4*)&L[(size_t)(n0 + n) * 1024 + k0 + c4] = l;
    }
}

// ---------------------------------------------------------------------------
// K fp32 (B,S,H*D) -> bf16 hi/lo 64x64 tiles, frag-major for 32x32x16 A-op.
// Frag f = ds*2 + kvt: element (kv = kvt*32 + (lane&31), d = ds*16 + (lane>>5)*8 + j)
// ---------------------------------------------------------------------------
__global__ __launch_bounds__(256) void kv_convert_kernel(
    const float* __restrict__ kw,
    ushortT* __restrict__ KhG, ushortT* __restrict__ KlG)
{
    const int jb = blockIdx.x, bh = blockIdx.y;
    const int b = bh >> 4, h = bh & 15;

    __shared__ float T[64][68];
    const int tid = threadIdx.x;
    const size_t ibase = (size_t)b * SS * DIM + (size_t)h * HD + (size_t)(jb * 64) * DIM;
    const int c4 = (tid & 15) * 4;
#pragma unroll
    for (int i = 0; i < 4; i++) {
        int r = (tid >> 4) + 16 * i;
        *(float4*)&T[r][c4] = *(const float4*)(kw + ibase + (size_t)r * DIM + c4);
    }
    __syncthreads();

    ushortT* oh = KhG + (size_t)(bh * 32 + jb) * 4096;
    ushortT* ol = KlG + (size_t)(bh * 32 + jb) * 4096;

#pragma unroll
    for (int i = 0; i < 2; i++) {
        const int s = tid + i * 256;          // slot 0..511
        const int f = s >> 6;                 // frag 0..7
        const int lane = s & 63;
        const int ds = f >> 1, kvt = f & 1;
        const int kv = kvt * 32 + (lane & 31);
        const int d0 = ds * 16 + (lane >> 5) * 8;
        ushortT hv[8], lv[8];
#pragma unroll
        for (int j = 0; j < 8; j++) split_tr(T[kv][d0 + j], hv[j], lv[j]);
        *(short4*)&oh[s * 8]     = *(short4*)&hv[0];
        *(short4*)&oh[s * 8 + 4] = *(short4*)&hv[4];
        *(short4*)&ol[s * 8]     = *(short4*)&lv[0];
        *(short4*)&ol[s * 8 + 4] = *(short4*)&lv[4];
    }
}

// ---------------------------------------------------------------------------
// Split-bf16 MFMA GEMM, 128x128 tile. z==2 (V projection) stores its output
// DIRECTLY as split-bf16 frag-major 32x32x16 V^T A-op tiles. z==0/1 fp32 rows.
// BK=64 + both-sides XOR swizzle (round-7) + XCD-chunked remap (round-8).
// launch_bounds (256,2): 2 blocks/CU (VGPR-capped; (256,3) cost ~18 µs).
// Round-6 lesson: K-projection fusion here was net-negative; kv_convert kept.
// ---------------------------------------------------------------------------
__global__ __launch_bounds__(256, 2) void gemm_bt_split_kernel(
    const ushortT* __restrict__ Ah, const ushortT* __restrict__ Al,
    const ushortT* __restrict__ BtH, const ushortT* __restrict__ BtL,
    float* __restrict__ Y0, float* __restrict__ Y1,
    ushortT* __restrict__ VhG, ushortT* __restrict__ VlG)
{
    const int z = blockIdx.z;
    const ushortT* __restrict__ Bh = BtH + (size_t)z * 1024 * 1024;
    const ushortT* __restrict__ Bl = BtL + (size_t)z * 1024 * 1024;

    const int K = 1024, N = 1024;
    // XCD-chunked remap (bijective, grid 8x32 per z; 256%8==0):
    const int wid  = blockIdx.x + (blockIdx.y << 3);
    const int work = ((wid & 7) << 5) + (wid >> 3);
    const int m0 = (work >> 3) * 128;
    const int n0 = (work & 7) * 128;

    __shared__ __align__(16) ushortT AhS[128 * 64];
    __shared__ __align__(16) ushortT AlS[128 * 64];
    __shared__ __align__(16) ushortT BhS[128 * 64];
    __shared__ __align__(16) ushortT BlS[128 * 64];

    const int tid  = threadIdx.x;
    const int wave = tid >> 6, lane = tid & 63;
    const int quad = lane >> 4, l15 = lane & 15;
    const int wm = wave >> 1, wn = wave & 1;
    const int rx = l15 & 7;                 // read-side swizzle key

    float4v acc[4][4];
#pragma unroll
    for (int i = 0; i < 4; i++)
#pragma unroll
        for (int j = 0; j < 4; j++) acc[i][j] = (float4v){0.f, 0.f, 0.f, 0.f};

    for (int k0 = 0; k0 < K; k0 += 64) {
        __syncthreads();
#pragma unroll
        for (int i = 0; i < 4; i++) {
            const int s = tid + i * 256;    // slot 0..1023: row r = s>>3, blk = s&7
            const int r = s >> 3;
            // swizzle: LDS 16B-block (r, s&7) holds global k-block ((s&7) ^ (r&7))
            const int kk = ((s & 7) ^ (r & 7)) * 8;
            gld_lds16(Ah + (size_t)(m0 + r) * K + k0 + kk, &AhS[s * 8]);
            gld_lds16(Al + (size_t)(m0 + r) * K + k0 + kk, &AlS[s * 8]);
            gld_lds16(Bh + (size_t)(n0 + r) * K + k0 + kk, &BhS[s * 8]);
            gld_lds16(Bl + (size_t)(n0 + r) * K + k0 + kk, &BlS[s * 8]);
        }
        __syncthreads();

#pragma unroll
        for (int ks = 0; ks < 2; ks++) {
            FragU ah[4], al[4], bh[4], bl[4];
#pragma unroll
            for (int t = 0; t < 4; t++) {
                const int ra = wm * 64 + t * 16 + l15;   // ra&7 == rx
                const int rb = wn * 64 + t * 16 + l15;
                const int boff = ((ks * 4 + quad) ^ rx) * 8;
                ah[t].v = *(const short8v*)&AhS[ra * 64 + boff];
                al[t].v = *(const short8v*)&AlS[ra * 64 + boff];
                bh[t].v = *(const short8v*)&BhS[rb * 64 + boff];
                bl[t].v = *(const short8v*)&BlS[rb * 64 + boff];
            }
#pragma unroll
            for (int mt = 0; mt < 4; mt++)
#pragma unroll
                for (int nt = 0; nt < 4; nt++) {
                    acc[mt][nt] = __builtin_amdgcn_mfma_f32_16x16x32_bf16(ah[mt].v, bh[nt].v, acc[mt][nt], 0, 0, 0);
                    acc[mt][nt] = __builtin_amdgcn_mfma_f32_16x16x32_bf16(ah[mt].v, bl[nt].v, acc[mt][nt], 0, 0, 0);
                    acc[mt][nt] = __builtin_amdgcn_mfma_f32_16x16x32_bf16(al[mt].v, bh[nt].v, acc[mt][nt], 0, 0, 0);
                }
        }
    }

    if (z == 2) {
        // ---- V epilogue: direct frag-major split-bf16 V^T A-op tile store ----
        const int b  = m0 >> 11;
        const int jb = ((m0 & 2047) >> 6) + wm;
        const int h  = (n0 >> 6) + wn;
        const size_t tb = (size_t)((b * 16 + h) * 32 + jb) * 4096;
        ushortT* vh = VhG + tb;
        ushortT* vl = VlG + tb;
#pragma unroll
        for (int mt = 0; mt < 4; mt++)
#pragma unroll
            for (int nt = 0; nt < 4; nt++) {
                const int off = ((((nt >> 1) * 4 + mt) * 64 +
                                  (quad >> 1) * 32 + (nt & 1) * 16 + l15) * 8) +
                                (quad & 1) * 4;
                float4 vv = make_float4(acc[mt][nt][0], acc[mt][nt][1],
                                        acc[mt][nt][2], acc[mt][nt][3]);
                unsigned short h0, l0, h1, l1, h2, l2, h3, l3;
                split_tr(vv.x, h0, l0); split_tr(vv.y, h1, l1);
                split_tr(vv.z, h2, l2); split_tr(vv.w, h3, l3);
                *(short4*)&vh[off] = make_short4((short)h0, (short)h1, (short)h2, (short)h3);
                *(short4*)&vl[off] = make_short4((short)l0, (short)l1, (short)l2, (short)l3);
            }
    } else {
        float* __restrict__ Y = (z == 0) ? Y0 : Y1;
#pragma unroll
        for (int mt = 0; mt < 4; mt++)
#pragma unroll
            for (int r = 0; r < 4; r++) {
                const int row = m0 + wm * 64 + mt * 16 + quad * 4 + r;
                float* yp = Y + (size_t)row * N + n0 + wn * 64 + l15;
#pragma unroll
                for (int nt = 0; nt < 4; nt++)
                    yp[nt * 16] = acc[mt][nt][r];
            }
    }
}

// ---------------------------------------------------------------------------
// Round-9: BM=64 x BN=128 split-bf16 GEMM for the OUTPUT PROJECTION only.
// The old path ran dim3(8,32)=256 blocks = 1 block/CU (zero cross-block
// latency hiding). This tile gives 512 blocks = 2+/CU, LDS 48 KB (up to 3
// resident), acc[4][2] (32 VGPR). Same BK=64 + both-sides XOR swizzle +
// XCD-chunked remap. Per-output K-accumulation order identical to the 128^2
// kernel -> bit-identical fp32 result.
// ---------------------------------------------------------------------------
__global__ __launch_bounds__(256, 2) void gemm_bt64_kernel(
    const ushortT* __restrict__ Ah, const ushortT* __restrict__ Al,
    const ushortT* __restrict__ Bh, const ushortT* __restrict__ Bl,
    float* __restrict__ Y)
{
    const int K = 1024, N = 1024;
    // grid 8 x 64 = 512; XCD-chunk: XCD x owns works [64x,64x+64) =
    // m-panels [8x,8x+8) -> A footprint 2MB L2-resident.
    const int wid  = blockIdx.x + (blockIdx.y << 3);
    const int work = ((wid & 7) << 6) + (wid >> 3);
    const int m0 = (work >> 3) * 64;
    const int n0 = (work & 7) * 128;

    __shared__ __align__(16) ushortT AhS[64 * 64];
    __shared__ __align__(16) ushortT AlS[64 * 64];
    __shared__ __align__(16) ushortT BhS[128 * 64];
    __shared__ __align__(16) ushortT BlS[128 * 64];

    const int tid  = threadIdx.x;
    const int wave = tid >> 6, lane = tid & 63;
    const int quad = lane >> 4, l15 = lane & 15;
    const int rx = l15 & 7;

    float4v acc[4][2];
#pragma unroll
    for (int i = 0; i < 4; i++)
#pragma unroll
        for (int j = 0; j < 2; j++) acc[i][j] = (float4v){0.f, 0.f, 0.f, 0.f};

    for (int k0 = 0; k0 < K; k0 += 64) {
        __syncthreads();
        // A: 512 slots (rows 0..63), B: 1024 slots (rows 0..127)
#pragma unroll
        for (int i = 0; i < 2; i++) {
            const int s = tid + i * 256;
            const int r = s >> 3;
            const int kk = ((s & 7) ^ (r & 7)) * 8;
            gld_lds16(Ah + (size_t)(m0 + r) * K + k0 + kk, &AhS[s * 8]);
            gld_lds16(Al + (size_t)(m0 + r) * K + k0 + kk, &AlS[s * 8]);
        }
#pragma unroll
        for (int i = 0; i < 4; i++) {
            const int s = tid + i * 256;
            const int r = s >> 3;
            const int kk = ((s & 7) ^ (r & 7)) * 8;
            gld_lds16(Bh + (size_t)(n0 + r) * K + k0 + kk, &BhS[s * 8]);
            gld_lds16(Bl + (size_t)(n0 + r) * K + k0 + kk, &BlS[s * 8]);
        }
        __syncthreads();

#pragma unroll
        for (int ks = 0; ks < 2; ks++) {
            FragU ah[4], al[4], bh[2], bl[2];
#pragma unroll
            for (int t = 0; t < 4; t++) {
                const int ra = t * 16 + l15;             // ra&7 == rx
                const int boff = ((ks * 4 + quad) ^ rx) * 8;
                ah[t].v = *(const short8v*)&AhS[ra * 64 + boff];
                al[t].v = *(const short8v*)&AlS[ra * 64 + boff];
            }
#pragma unroll
            for (int t = 0; t < 2; t++) {
                const int rb = wave * 32 + t * 16 + l15; // rb&7 == rx
                const int boff = ((ks * 4 + quad) ^ rx) * 8;
                bh[t].v = *(const short8v*)&BhS[rb * 64 + boff];
                bl[t].v = *(const short8v*)&BlS[rb * 64 + boff];
            }
#pragma unroll
            for (int mt = 0; mt < 4; mt++)
#pragma unroll
                for (int nt = 0; nt < 2; nt++) {
                    acc[mt][nt] = __builtin_amdgcn_mfma_f32_16x16x32_bf16(ah[mt].v, bh[nt].v, acc[mt][nt], 0, 0, 0);
                    acc[mt][nt] = __builtin_amdgcn_mfma_f32_16x16x32_bf16(ah[mt].v, bl[nt].v, acc[mt][nt], 0, 0, 0);
                    acc[mt][nt] = __builtin_amdgcn_mfma_f32_16x16x32_bf16(al[mt].v, bh[nt].v, acc[mt][nt], 0, 0, 0);
                }
        }
    }

#pragma unroll
    for (int mt = 0; mt < 4; mt++)
#pragma unroll
        for (int r = 0; r < 4; r++) {
            const int row = m0 + mt * 16 + quad * 4 + r;
            float* yp = Y + (size_t)row * N + n0 + wave * 32 + l15;
#pragma unroll
            for (int nt = 0; nt < 2; nt++)
                yp[nt * 16] = acc[mt][nt][r];
        }
}

// ---------------------------------------------------------------------------
// MFMA attention, 32x32x16. Round-9 = round-8 verbatim (verified 113.7 µs,
// FETCH 24.7MB): XCD-chunked remap + W-form accumulator + round-4 pipeline
// (QK(jb+1) before finish(jb); K 2-ahead, V 1-ahead; 1 barrier/iter).
// NO setprio (round-5: cost 2.9 µs). Per-step division is SEMANTIC (round-2);
// W-form carries it exactly: W_t = (al_t/l_{t-1})W_{t-1} + P_t V_t, O = W/l_T.
// ---------------------------------------------------------------------------
__global__ __launch_bounds__(256, 2) void attn_mfma_kernel(
    const float* __restrict__ q,
    const ushortT* __restrict__ KhG, const ushortT* __restrict__ KlG,
    const ushortT* __restrict__ VhG, const ushortT* __restrict__ VlG,
    ushortT* __restrict__ Oh, ushortT* __restrict__ Ol)
{
    // layout (ushort units): K0 @0, K1 @8192, V0 @16384, V1 @24576
    __shared__ __align__(16) ushortT SMEM[32768];   // 64 KiB

    const int tid  = threadIdx.x;
    const int wave = tid >> 6, lane = tid & 63;
    const int l31 = lane & 31, hi5 = lane >> 5;
    const int wid  = blockIdx.x + (blockIdx.y << 4);
    const int work = ((wid & 7) << 6) + (wid >> 3);
    const int qx = work & 15;
    const int bh = work >> 4;
    const int b = bh >> 4, h = bh & 15;
    const size_t base = (size_t)b * SS * DIM + (size_t)h * HD;
    const int qs0 = qx * 128 + wave * 32;
    const int lane8 = lane * 8;
    const int sl0 = wave * 128 + lane, sl1 = sl0 + 64;

    ushortT* K0 = SMEM;
    ushortT* K1 = SMEM + 8192;
    ushortT* V0 = SMEM + 16384;
    ushortT* V1 = SMEM + 24576;

    // ---- Q fragments (B-op: n = q = l31, k = d = ds*16 + hi5*8 + j) ----
    const float qscale = 0.125f * 1.4426950408889634f;
    FragU Qh[4], Ql[4];
    {
        const int qrow = qs0 + l31;
#pragma unroll
        for (int ds = 0; ds < 4; ds++) {
            const float* p0 = q + base + (size_t)qrow * DIM + ds * 16 + hi5 * 8;
            float4 a = *(const float4*)(p0);
            float4 c = *(const float4*)(p0 + 4);
            float e[8] = {a.x, a.y, a.z, a.w, c.x, c.y, c.z, c.w};
#pragma unroll
            for (int j = 0; j < 8; j++) {
                float x = e[j] * qscale;
                unsigned short hs = f2bf(x);
                Qh[ds].us[j] = hs;
                Ql[ds].us[j] = f2bf(x - bf2f(hs));
            }
        }
    }

    // W accumulators (= l_run * O): tile dt covers d = dt*32 + row, col q = l31
    float16v Oacc[2];
#pragma unroll
    for (int dt = 0; dt < 2; dt++)
        Oacc[dt] = (float16v){0.f,0.f,0.f,0.f,0.f,0.f,0.f,0.f,
                              0.f,0.f,0.f,0.f,0.f,0.f,0.f,0.f};

    float m_run = -INFINITY;
    float l_run = 0.f;
    float inv_prev = 1.0f;   // 1/l_{t-1}; arbitrary at t=0 (al=0 kills it)

    auto stage_K = [&](int t, ushortT* dst) {
        const size_t tb = (size_t)(bh * 32 + t) * 4096;
        gld_lds16(KhG + tb + sl0 * 8, &dst[sl0 * 8]);
        gld_lds16(KhG + tb + sl1 * 8, &dst[sl1 * 8]);
        gld_lds16(KlG + tb + sl0 * 8, &dst[4096 + sl0 * 8]);
        gld_lds16(KlG + tb + sl1 * 8, &dst[4096 + sl1 * 8]);
    };
    auto stage_V = [&](int t, ushortT* dst) {
        const size_t tb = (size_t)(bh * 32 + t) * 4096;
        gld_lds16(VhG + tb + sl0 * 8, &dst[sl0 * 8]);
        gld_lds16(VhG + tb + sl1 * 8, &dst[sl1 * 8]);
        gld_lds16(VlG + tb + sl0 * 8, &dst[4096 + sl0 * 8]);
        gld_lds16(VlG + tb + sl1 * 8, &dst[4096 + sl1 * 8]);
    };

    auto qk = [&](const ushortT* Kb, float16v (&st)[2]) {
        const ushortT* KhS = Kb;
        const ushortT* KlS = Kb + 4096;
#pragma unroll
        for (int t = 0; t < 2; t++)
            st[t] = (float16v){0.f,0.f,0.f,0.f,0.f,0.f,0.f,0.f,
                               0.f,0.f,0.f,0.f,0.f,0.f,0.f,0.f};
#pragma unroll
        for (int ds = 0; ds < 4; ds++) {
            FragU kh0, kl0, kh1, kl1;
            kh0.v = *(const short8v*)&KhS[(ds * 2 + 0) * 512 + lane8];
            kl0.v = *(const short8v*)&KlS[(ds * 2 + 0) * 512 + lane8];
            kh1.v = *(const short8v*)&KhS[(ds * 2 + 1) * 512 + lane8];
            kl1.v = *(const short8v*)&KlS[(ds * 2 + 1) * 512 + lane8];
            st[0] = __builtin_amdgcn_mfma_f32_32x32x16_bf16(kh0.v, Qh[ds].v, st[0], 0, 0, 0);
            st[0] = __builtin_amdgcn_mfma_f32_32x32x16_bf16(kh0.v, Ql[ds].v, st[0], 0, 0, 0);
            st[0] = __builtin_amdgcn_mfma_f32_32x32x16_bf16(kl0.v, Qh[ds].v, st[0], 0, 0, 0);
            st[1] = __builtin_amdgcn_mfma_f32_32x32x16_bf16(kh1.v, Qh[ds].v, st[1], 0, 0, 0);
            st[1] = __builtin_amdgcn_mfma_f32_32x32x16_bf16(kh1.v, Ql[ds].v, st[1], 0, 0, 0);
            st[1] = __builtin_amdgcn_mfma_f32_32x32x16_bf16(kl1.v, Qh[ds].v, st[1], 0, 0, 0);
        }
    };

    auto finish = [&](float16v (&st)[2], const ushortT* Vb) {
        const ushortT* VhS = Vb;
        const ushortT* VlS = Vb + 4096;
        float wscale;
        {
            float g[8];
#pragma unroll
            for (int t = 0; t < 2; t++)
#pragma unroll
                for (int i = 0; i < 4; i++)
                    g[t * 4 + i] = fmaxf(fmaxf(st[t][4 * i], st[t][4 * i + 1]),
                                         fmaxf(st[t][4 * i + 2], st[t][4 * i + 3]));
            float vmax = fmaxf(fmaxf(fmaxf(g[0], g[1]), fmaxf(g[2], g[3])),
                               fmaxf(fmaxf(g[4], g[5]), fmaxf(g[6], g[7])));
            vmax = fmaxf(vmax, __shfl_xor(vmax, 32, 64));
            const float mn = fmaxf(m_run, vmax);
            const float al = __builtin_amdgcn_exp2f(m_run - mn);   // 0 on first iter

            float ssum = 0.f;
#pragma unroll
            for (int t = 0; t < 2; t++)
#pragma unroll
                for (int r = 0; r < 16; r++) {
                    const float p = __builtin_amdgcn_exp2f(st[t][r] - mn);
                    st[t][r] = p;
                    ssum += p;
                }
            ssum += __shfl_xor(ssum, 32, 64);
            const float ln = al * l_run + ssum;
            wscale = al * inv_prev;          // al / l_{t-1}: carries prev division
            inv_prev = __builtin_amdgcn_rcpf(ln);
            m_run = mn;
            l_run = ln;
        }

#pragma unroll
        for (int dt = 0; dt < 2; dt++)
#pragma unroll
            for (int r = 0; r < 16; r++)
                Oacc[dt][r] *= wscale;

#pragma unroll
        for (int kvs = 0; kvs < 4; kvs++) {
            const int kvt = kvs >> 1;
            const int R = (kvs & 1) * 8;
            float p0 = st[kvt][R + 0], p1 = st[kvt][R + 1];
            float p2 = st[kvt][R + 2], p3 = st[kvt][R + 3];
            float p4 = st[kvt][R + 4], p5 = st[kvt][R + 5];
            float p6 = st[kvt][R + 6], p7 = st[kvt][R + 7];
            unsigned X0 = cvt_pk_bf16(p0, p1), X1 = cvt_pk_bf16(p2, p3);
            unsigned Y0 = cvt_pk_bf16(p4, p5), Y1 = cvt_pk_bf16(p6, p7);
            float e0 = p0 - __builtin_bit_cast(float, X0 << 16);
            float e1 = p1 - __builtin_bit_cast(float, X0 & 0xffff0000u);
            float e2 = p2 - __builtin_bit_cast(float, X1 << 16);
            float e3 = p3 - __builtin_bit_cast(float, X1 & 0xffff0000u);
            float e4 = p4 - __builtin_bit_cast(float, Y0 << 16);
            float e5 = p5 - __builtin_bit_cast(float, Y0 & 0xffff0000u);
            float e6 = p6 - __builtin_bit_cast(float, Y1 << 16);
            float e7 = p7 - __builtin_bit_cast(float, Y1 & 0xffff0000u);
            unsigned Z0 = cvt_pk_bf16(e0, e1), Z1 = cvt_pk_bf16(e2, e3);
            unsigned W0 = cvt_pk_bf16(e4, e5), W1 = cvt_pk_bf16(e6, e7);
            permlane32_swap(X0, Y0);
            permlane32_swap(X1, Y1);
            permlane32_swap(Z0, W0);
            permlane32_swap(Z1, W1);
            FragU Phf, Plf;
            Phf.u[0] = X0; Phf.u[1] = X1; Phf.u[2] = Y0; Phf.u[3] = Y1;
            Plf.u[0] = Z0; Plf.u[1] = Z1; Plf.u[2] = W0; Plf.u[3] = W1;

#pragma unroll
            for (int dt = 0; dt < 2; dt++) {
                FragU vh, vl;
                vh.v = *(const short8v*)&VhS[(dt * 4 + kvs) * 512 + lane8];
                vl.v = *(const short8v*)&VlS[(dt * 4 + kvs) * 512 + lane8];
                Oacc[dt] = __builtin_amdgcn_mfma_f32_32x32x16_bf16(vh.v, Phf.v, Oacc[dt], 0, 0, 0);
                Oacc[dt] = __builtin_amdgcn_mfma_f32_32x32x16_bf16(vl.v, Phf.v, Oacc[dt], 0, 0, 0);
                Oacc[dt] = __builtin_amdgcn_mfma_f32_32x32x16_bf16(vh.v, Plf.v, Oacc[dt], 0, 0, 0);
            }
        }
    };

    float16v stA[2], stB[2];

    // ---- prologue: publish K(0), K(1), V(0); compute S(0) ----
    stage_K(0, K0);
    stage_K(1, K1);
    stage_V(0, V0);
    __syncthreads();                 // vmcnt drain + publish K0,K1,V0
    qk(K0, stA);
    __syncthreads();                 // all waves done reading K0 (free for K(2))

    auto iter = [&](int jb, float16v (&SC)[2], float16v (&SN)[2],
                    ushortT* Kc, ushortT* Kn, ushortT* Vc, ushortT* Vn) {
        if (jb <= 29) stage_K(jb + 2, Kc);
        if (jb <= 30) stage_V(jb + 1, Vn);
        if (jb <= 30) qk(Kn, SN);    // MFMA on jb+1 — overlaps finish(jb)'s VALU
        finish(SC, Vc);              // stats+pack (VALU) + PV (MFMA) for jb
        __syncthreads();             // drains vmcnt; publishes K(jb+2), V(jb+1)
    };

    for (int jb = 0; jb < 32; jb += 2) {
        iter(jb,     stA, stB, K0, K1, V0, V1);
        iter(jb + 1, stB, stA, K1, K0, V1, V0);
    }

    // ---- deferred final division: O = W * (1/l_last) ----
#pragma unroll
    for (int dt = 0; dt < 2; dt++)
#pragma unroll
        for (int r = 0; r < 16; r++)
            Oacc[dt][r] *= inv_prev;

    // ---- epilogue: transpose O^T per tile via wave-local LDS (reuse SMEM),
    //      split-bf16 coalesced store ----
    float* EP = ((float*)SMEM) + wave * 1056;   // [32 q][33 f32] per wave
    const int qq = lane >> 1, dh = (lane & 1) * 16;
#pragma unroll
    for (int dt = 0; dt < 2; dt++) {
#pragma unroll
        for (int g = 0; g < 4; g++) {
            float4 wv = make_float4(Oacc[dt][4 * g + 0], Oacc[dt][4 * g + 1],
                                    Oacc[dt][4 * g + 2], Oacc[dt][4 * g + 3]);
            *(float4*)&EP[l31 * 33 + g * 8 + hi5 * 4] = wv;
        }
        // wave-local region: lgkmcnt orders write->read, no barrier
        float vals[16];
#pragma unroll
        for (int k4 = 0; k4 < 4; k4++)
            *(float4*)&vals[k4 * 4] = *(const float4*)&EP[qq * 33 + dh + k4 * 4];

        unsigned ho[8], lo8[8];
#pragma unroll
        for (int kk = 0; kk < 8; kk++) {
            unsigned short h0, l0, h1, l1;
            split_tr(vals[2 * kk], h0, l0);
            split_tr(vals[2 * kk + 1], h1, l1);
            ho[kk]  = (unsigned)h0 | ((unsigned)h1 << 16);
            lo8[kk] = (unsigned)l0 | ((unsigned)l1 << 16);
        }
        const int qrow = qs0 + qq;
        const size_t off = (size_t)(b * SS + qrow) * DIM + h * HD + dt * 32 + dh;
        *(uint4*)&Oh[off]     = make_uint4(ho[0], ho[1], ho[2], ho[3]);
        *(uint4*)&Oh[off + 8] = make_uint4(ho[4], ho[5], ho[6], ho[7]);
        *(uint4*)&Ol[off]     = make_uint4(lo8[0], lo8[1], lo8[2], lo8[3]);
        *(uint4*)&Ol[off + 8] = make_uint4(lo8[4], lo8[5], lo8[6], lo8[7]);
    }
}

// ---------------------------------------------------------------------------
extern "C" void kernel_launch(void* const* d_in, const int* in_sizes, int n_in,
                              void* d_out, int out_size, void* d_ws, size_t ws_size,
                              hipStream_t stream)
{
    const float* x  = (const float*)d_in[0];
    const float* Wq = (const float*)d_in[1];
    const float* Wk = (const float*)d_in[2];
    const float* Wv = (const float*)d_in[3];
    const float* Wo = (const float*)d_in[4];
    float* out = (float*)d_out;

    char* w = (char*)d_ws;
    float*   qw  = (float*)(w);                        // 16 MB
    float*   kw  = (float*)(w + ((size_t)16 << 20));   // 16 MB (later Oh/Ol)
    ushortT* VhG = (ushortT*)(w + ((size_t)32 << 20)); // 8 MB (V frag tiles, from GEMM)
    ushortT* VlG = (ushortT*)(w + ((size_t)40 << 20)); // 8 MB
    ushortT* XhS = (ushortT*)(w + ((size_t)48 << 20)); // 8 MB
    ushortT* XlS = (ushortT*)(w + ((size_t)56 << 20)); // 8 MB
    ushortT* WtH = (ushortT*)(w + ((size_t)64 << 20)); // 8 MB (4 matrices)
    ushortT* WtL = (ushortT*)(w + ((size_t)72 << 20)); // 8 MB
    ushortT* KhG = (ushortT*)(w + ((size_t)80 << 20)); // 8 MB
    ushortT* KlG = (ushortT*)(w + ((size_t)88 << 20)); // 8 MB  -> 96 MB total
    ushortT* OhS = (ushortT*)kw;                       // reuse after kv_convert
    ushortT* OlS = (ushortT*)(w + ((size_t)24 << 20));

    dim3 blk(256);
    const int n4 = MTOT * DIM / 4;

    // split X -> bf16 hi/lo; transpose+split all four W
    convert_split_kernel<<<dim3(n4 / 256), blk, 0, stream>>>(x, XhS, XlS, n4);
    transpose_split_kernel<<<dim3(16, 16, 4), blk, 0, stream>>>(Wq, Wk, Wv, Wo, WtH, WtL);

    // Q/K/V projections; z==2 (V) emits frag-major split tiles directly
    gemm_bt_split_kernel<<<dim3(8, 32, 3), blk, 0, stream>>>(
        XhS, XlS, WtH, WtL, qw, kw, VhG, VlG);

    // K -> frag-major split tiles (32x32x16 A-op layout)
    kv_convert_kernel<<<dim3(32, 32), blk, 0, stream>>>(kw, KhG, KlG);

    // attention (exact reference recurrence, kv block = 64)
    attn_mfma_kernel<<<dim3(16, 32), blk, 0, stream>>>(qw, KhG, KlG, VhG, VlG, OhS, OlS);

    // output projection: BM=64 tile, 512 blocks = 2+/CU (was 256 = 1/CU)
    gemm_bt64_kernel<<<dim3(8, 64), blk, 0, stream>>>(
        OhS, OlS, WtH + (size_t)3 * 1024 * 1024, WtL + (size_t)3 * 1024 * 1024,
        out);
}